// Round 7
// baseline (754.100 us; speedup 1.0000x reference)
//
#include <hip/hip_runtime.h>
#include <hip/hip_bf16.h>

// Problem constants (from reference)
#define N_NODES 50000
#define N_EDGES 10000
#define NNZV    250000
#define IN_CH   128
#define HDIM    64
#define DSTALK  6
#define HD      384   // HDIM * DSTALK
#define NROWS   (N_NODES * DSTALK)   // 300000
#define EROWS   (N_EDGES * DSTALK)   // 60000

// ---------------------------------------------------------------------------
// W-prep 1: W0effT[j][k] = sum_m W_lin[k][r*64+m] * W0[m][h]  (j=r*64+h)
// transposed [384][128] so the GEMM can vector-load along k.
__global__ __launch_bounds__(256) void k_wefft(
    const float* __restrict__ W_lin, const float* __restrict__ W0,
    float* __restrict__ W0effT) {
  int idx = blockIdx.x * blockDim.x + threadIdx.x;
  if (idx >= IN_CH * HD) return;
  int k = idx / HD, j = idx - k * HD;
  int r = j >> 6, h = j & 63;
  float s = 0.f;
#pragma unroll 8
  for (int m = 0; m < HDIM; m++)
    s += W_lin[k * HD + r * HDIM + m] * W0[m * HDIM + h];
  W0effT[(size_t)j * IN_CH + k] = s;
}

// W-prep 2: Wm, cm, c0 + sheaf tables gwN/gwE/G/K + W1T transpose
#define WS_BASE (IN_CH * HDIM + HD + HDIM)   // 8640
#define WS_END  (WS_BASE + 780 + HDIM * HDIM)
__global__ __launch_bounds__(256) void k_wsmall(
    const float* __restrict__ W_lin, const float* __restrict__ b_lin,
    const float* __restrict__ W0, const float* __restrict__ W1,
    const float* __restrict__ g, const float* __restrict__ bln,
    const float* __restrict__ Ws, const float* __restrict__ bs,
    float* __restrict__ Wm, float* __restrict__ cm, float* __restrict__ c0,
    float* __restrict__ gwN, float* __restrict__ gwE,
    float* __restrict__ G, float* __restrict__ K, float* __restrict__ W1T) {
  int idx = blockIdx.x * blockDim.x + threadIdx.x;
  if (idx < IN_CH * HDIM) {            // Wm
    int k = idx >> 6, h = idx & 63;
    float s = 0.f;
#pragma unroll
    for (int r = 0; r < DSTALK; r++) s += W_lin[k * HD + r * HDIM + h];
    Wm[idx] = s * (1.f / 6.f);
  } else if (idx < IN_CH * HDIM + HD) {  // c0
    int j = idx - IN_CH * HDIM;
    int r = j >> 6, h = j & 63;
    float s = 0.f;
#pragma unroll 8
    for (int m = 0; m < HDIM; m++) s += b_lin[r * HDIM + m] * W0[m * HDIM + h];
    c0[j] = s;
  } else if (idx < WS_BASE) {  // cm
    int h = idx - IN_CH * HDIM - HD;
    float s = 0.f;
#pragma unroll
    for (int r = 0; r < DSTALK; r++) s += b_lin[r * HDIM + h];
    cm[h] = s * (1.f / 6.f);
  } else if (idx < WS_BASE + 384) {      // gwN
    int i = idx - WS_BASE;
    int h = i / 6, r = i - h * 6;
    gwN[i] = g[h] * Ws[h * DSTALK + r];
  } else if (idx < WS_BASE + 768) {      // gwE
    int i = idx - WS_BASE - 384;
    int h = i / 6, r = i - h * 6;
    gwE[i] = g[64 + h] * Ws[(64 + h) * DSTALK + r];
  } else if (idx < WS_BASE + 774) {      // G
    int r = idx - WS_BASE - 768;
    float s = 0.f;
    for (int i = 0; i < 2 * HDIM; i++) s += g[i] * Ws[i * DSTALK + r];
    G[r] = s;
  } else if (idx < WS_BASE + 780) {      // K
    int r = idx - WS_BASE - 774;
    float s = 0.f;
    for (int i = 0; i < 2 * HDIM; i++) s += bln[i] * Ws[i * DSTALK + r];
    K[r] = s + bs[r];
  } else if (idx < WS_END) {             // W1T[c][k] = W1[k][c]
    int i = idx - WS_BASE - 780;
    int c = i >> 6, k = i & 63;
    W1T[c * HDIM + k] = W1[k * HDIM + c];
  }
}

// ---------------------------------------------------------------------------
// Fused: row features xa = [x;hea]@Wm + cm (LDS only) -> per-row stats
__global__ __launch_bounds__(256) void k_xa_stats(
    const float* __restrict__ x, const float* __restrict__ ea,
    const float* __restrict__ Wm, const float* __restrict__ cm,
    const float* __restrict__ gwN, const float* __restrict__ gwE,
    float* __restrict__ stats) {
  __shared__ float lx[64][IN_CH];      // 32 KB input tile
  __shared__ float ox[64][HDIM + 1];   // 16.6 KB feature tile (padded)
  __shared__ float lgw[2][64 * DSTALK];
  const int row0 = blockIdx.x * 64;
  const int tid = threadIdx.x;
  for (int i = tid; i < 2 * 64 * DSTALK; i += 256) {
    int which = i / 384, k = i - which * 384;
    lgw[which][k] = which ? gwE[k] : gwN[k];
  }
  for (int i = tid; i < 64 * IN_CH; i += 256) {
    int r = i >> 7, k = i & 127;
    int row = row0 + r;
    float v = 0.f;
    if (row < N_NODES) v = x[row * IN_CH + k];
    else if (row < N_NODES + N_EDGES) v = ea[(row - N_NODES) * IN_CH + k];
    lx[r][k] = v;
  }
  __syncthreads();
  const int col = tid & 63, rg = tid >> 6;  // 4 groups x 16 rows
  float acc[16];
#pragma unroll
  for (int i = 0; i < 16; i++) acc[i] = 0.f;
  for (int k = 0; k < IN_CH; k++) {
    float w = Wm[k * HDIM + col];
#pragma unroll
    for (int i = 0; i < 16; i++) acc[i] += lx[rg * 16 + i][k] * w;
  }
  const float c = cm[col];
#pragma unroll
  for (int i = 0; i < 16; i++) ox[rg * 16 + i][col] = acc[i] + c;
  __syncthreads();
  // 512 reduction tasks: (row, stat). stat: 0=s1, 1=s2, 2..7=p[r]
  for (int t = tid; t < 512; t += 256) {
    int row = t >> 3, st = t & 7;
    int grow = row0 + row;
    if (grow >= N_NODES + N_EDGES) continue;
    const float* __restrict__ gw = (grow >= N_NODES) ? lgw[1] : lgw[0];
    float s = 0.f;
    if (st == 0) {
#pragma unroll 8
      for (int h = 0; h < HDIM; h++) s += ox[row][h];
    } else if (st == 1) {
#pragma unroll 8
      for (int h = 0; h < HDIM; h++) { float v = ox[row][h]; s += v * v; }
    } else {
      int r = st - 2;
#pragma unroll 8
      for (int h = 0; h < HDIM; h++) s += ox[row][h] * gw[h * DSTALK + r];
    }
    stats[(size_t)grow * 8 + st] = s;
  }
}

// ---------------------------------------------------------------------------
// Register-tiled fp32 GEMM: xl0[row][col] = x[row][:] . W0effT[col][:] + c0
// 128x128 tile per block, 8x8 per thread, BK=32.
// v2 (round 7): A read DIRECT from global (L1-resident: within a wave only 4
// distinct 16B lines per load since 16 lanes share tr; per-kc footprint
// 128rowsx128B=16KB fits L1). Only B staged in LDS -> DS traffic halves
// (16->8 ds_read_b128 per kq) and A-staging phase disappears. A processed in
// two groups of 4 to keep peak live set ~115 regs, all within one kq
// iteration (the only pattern that has not spilled: r1/r2/r5 ledger).
__global__ __launch_bounds__(256, 2) void k_xl0(
    const float* __restrict__ x, const float* __restrict__ W0effT,
    const float* __restrict__ c0, float* __restrict__ xl0) {
  __shared__ float4 bS[8][129];   // [kq][col], pad residue 4 -> 0-conflict (measured)
  const int tid = threadIdx.x;
  const int row0 = blockIdx.x * 128;
  const int col0 = blockIdx.y * 128;
  const int tc = tid & 15, tr = tid >> 4;   // 16x16 thread grid
  float acc[8][8];
#pragma unroll
  for (int i = 0; i < 8; i++)
#pragma unroll
    for (int j = 0; j < 8; j++) acc[i][j] = 0.f;

#pragma unroll 1
  for (int kc = 0; kc < 4; kc++) {
    if (kc) __syncthreads();
    // stage B only: 1024 float4 (4/thread)
#pragma unroll
    for (int i = 0; i < 4; i++) {
      int fidx = tid + (i << 8);         // 0..1023
      int kq = fidx & 7, col = fidx >> 3;
      int gk = kc * 32 + kq * 4;
      bS[kq][col] =
          *(const float4*)(W0effT + (size_t)(col0 + col) * IN_CH + gk);
    }
    __syncthreads();
#pragma unroll 1
    for (int kq = 0; kq < 8; kq++) {
      const int gk = kc * 32 + kq * 4;
      float4 b[8];
#pragma unroll
      for (int j = 0; j < 8; j++) b[j] = bS[kq][tc + (j << 4)];
      // A half 0: rows tr+0..tr+48
      {
        float4 a[4];
#pragma unroll
        for (int i = 0; i < 4; i++) {
          int grow = row0 + tr + (i << 4);
          a[i] = (grow < N_NODES)
                     ? *(const float4*)(x + (size_t)grow * IN_CH + gk)
                     : make_float4(0.f, 0.f, 0.f, 0.f);
        }
#pragma unroll
        for (int i = 0; i < 4; i++)
#pragma unroll
          for (int j = 0; j < 8; j++)
            acc[i][j] += a[i].x * b[j].x + a[i].y * b[j].y +
                         a[i].z * b[j].z + a[i].w * b[j].w;
      }
      // A half 1: rows tr+64..tr+112
      {
        float4 a[4];
#pragma unroll
        for (int i = 0; i < 4; i++) {
          int grow = row0 + tr + ((i + 4) << 4);
          a[i] = (grow < N_NODES)
                     ? *(const float4*)(x + (size_t)grow * IN_CH + gk)
                     : make_float4(0.f, 0.f, 0.f, 0.f);
        }
#pragma unroll
        for (int i = 0; i < 4; i++)
#pragma unroll
          for (int j = 0; j < 8; j++)
            acc[i + 4][j] += a[i].x * b[j].x + a[i].y * b[j].y +
                             a[i].z * b[j].z + a[i].w * b[j].w;
      }
    }
  }

  float cc[8];
#pragma unroll
  for (int j = 0; j < 8; j++) cc[j] = c0[col0 + tc + (j << 4)];
#pragma unroll
  for (int i = 0; i < 8; i++) {
    int row = row0 + tr + (i << 4);
    if (row >= N_NODES) continue;
    float* __restrict__ orow = xl0 + (size_t)row * HD + col0;
#pragma unroll
    for (int j = 0; j < 8; j++) {
      orow[tc + (j << 4)] = acc[i][j] + cc[j];
    }
  }
}

// ---------------------------------------------------------------------------
// Register-tiled fp32 GEMM: xl = xin @ W1 (K=64, N=64). In-place safe (each
// block reads only its own rows + W1T, all reads precede its writes).
// v2 (round 7): W1T staged to LDS ONCE (16.6KB, single barrier pair); A read
// direct from global per kq (L1-resident; 4 distinct lines/load per wave).
__global__ __launch_bounds__(256) void k_xw(
    const float* __restrict__ xin, const float* __restrict__ W1T,
    float* __restrict__ xl) {
  __shared__ float4 bS[16][65];   // [kq][col] cols=64, K=64
  const int tid = threadIdx.x;
  const int row0 = blockIdx.x * 128;
  const int tc = tid & 15, tr = tid >> 4;
  // stage all of W1T: 1024 float4 (4/thread)
#pragma unroll
  for (int i = 0; i < 4; i++) {
    int fidx = tid + (i << 8);           // 0..1023
    int kq = fidx & 15, col = fidx >> 4; // col 0..63
    bS[kq][col] = *(const float4*)(W1T + col * HDIM + kq * 4);
  }
  __syncthreads();
  float acc[8][4];
#pragma unroll
  for (int i = 0; i < 8; i++)
#pragma unroll
    for (int j = 0; j < 4; j++) acc[i][j] = 0.f;

#pragma unroll 1
  for (int kq = 0; kq < 16; kq++) {
    const int gk = kq * 4;
    float4 b[4];
#pragma unroll
    for (int j = 0; j < 4; j++) b[j] = bS[kq][tc + (j << 4)];
    // A half 0
    {
      float4 a[4];
#pragma unroll
      for (int i = 0; i < 4; i++) {
        int grow = row0 + tr + (i << 4);
        a[i] = (grow < NROWS)
                   ? *(const float4*)(xin + (size_t)grow * HDIM + gk)
                   : make_float4(0.f, 0.f, 0.f, 0.f);
      }
#pragma unroll
      for (int i = 0; i < 4; i++)
#pragma unroll
        for (int j = 0; j < 4; j++)
          acc[i][j] += a[i].x * b[j].x + a[i].y * b[j].y +
                       a[i].z * b[j].z + a[i].w * b[j].w;
    }
    // A half 1
    {
      float4 a[4];
#pragma unroll
      for (int i = 0; i < 4; i++) {
        int grow = row0 + tr + ((i + 4) << 4);
        a[i] = (grow < NROWS)
                   ? *(const float4*)(xin + (size_t)grow * HDIM + gk)
                   : make_float4(0.f, 0.f, 0.f, 0.f);
      }
#pragma unroll
      for (int i = 0; i < 4; i++)
#pragma unroll
        for (int j = 0; j < 4; j++)
          acc[i + 4][j] += a[i].x * b[j].x + a[i].y * b[j].y +
                           a[i].z * b[j].z + a[i].w * b[j].w;
    }
  }
#pragma unroll
  for (int i = 0; i < 8; i++) {
    int row = row0 + tr + (i << 4);
    if (row >= NROWS) continue;
#pragma unroll
    for (int j = 0; j < 4; j++) {
      int col = tc + (j << 4);
      xl[(size_t)row * HDIM + col] = acc[i][j];
    }
  }
}

// ---------------------------------------------------------------------------
// closed-form sheaf coefficients: one THREAD per incidence
__global__ __launch_bounds__(256) void k_sheaf2(
    const int* __restrict__ nidx, const int* __restrict__ eidx,
    const float* __restrict__ stats,
    const float* __restrict__ G, const float* __restrict__ K,
    float* __restrict__ alpha) {
  int j = blockIdx.x * blockDim.x + threadIdx.x;
  if (j >= NNZV) return;
  int n = nidx[j], e = eidx[j];
  const float4* __restrict__ sn = (const float4*)(stats + (size_t)n * 8);
  const float4* __restrict__ se = (const float4*)(stats + ((size_t)(N_NODES + e)) * 8);
  float4 a0 = sn[0], a1 = sn[1];
  float4 b0 = se[0], b1 = se[1];
  float mu = (a0.x + b0.x) * (1.f / 128.f);
  float var = (a0.y + b0.y) * (1.f / 128.f) - mu * mu;
  float rs = rsqrtf(var + 1e-5f);
  float p[DSTALK] = {a0.z + b0.z, a0.w + b0.w, a1.x + b1.x,
                     a1.y + b1.y, a1.z + b1.z, a1.w + b1.w};
#pragma unroll
  for (int r = 0; r < DSTALK; r++) {
    float z = rs * (p[r] - mu * G[r]) + K[r];
    alpha[(size_t)j * DSTALK + r] = 1.f / (1.f + expf(-z));
  }
}

// ---------------------------------------------------------------------------
// degree counts
__global__ void k_count(const int* __restrict__ nidx, const int* __restrict__ eidx,
                        int* __restrict__ cntN, int* __restrict__ cntE) {
  int j = blockIdx.x * blockDim.x + threadIdx.x;
  if (j < NNZV) {
    atomicAdd(&cntN[nidx[j]], 1);
    atomicAdd(&cntE[eidx[j]], 1);
  }
}

// ---------------------------------------------------------------------------
// Multi-block exclusive scan, 512 elements/block.
__global__ __launch_bounds__(256) void k_scan_a(
    const int* __restrict__ cnt, int n, int* __restrict__ row,
    int* __restrict__ bsum) {
  const int b = blockIdx.x, t = threadIdx.x;
  const int i0 = b * 512 + 2 * t, i1 = i0 + 1;
  int c0 = (i0 < n) ? cnt[i0] : 0;
  int c1 = (i1 < n) ? cnt[i1] : 0;
  int ts = c0 + c1;
  const int lane = t & 63, wv = t >> 6;
  int s = ts;
#pragma unroll
  for (int o = 1; o < 64; o <<= 1) {
    int v = __shfl_up(s, o);
    if (lane >= o) s += v;
  }
  __shared__ int wsum[4];
  if (lane == 63) wsum[wv] = s;
  __syncthreads();
  int wbase = 0;
#pragma unroll
  for (int wprev = 0; wprev < 3; wprev++)
    if (wprev < wv) wbase += wsum[wprev];
  const int incl = wbase + s;
  const int excl = incl - ts;
  if (i0 < n) row[i0] = excl;
  if (i1 < n) row[i1] = excl + c0;
  if (t == 255) bsum[b] = incl;
}

__global__ __launch_bounds__(128) void k_scan_b(
    const int* __restrict__ bsum, int nb, int* __restrict__ bbase) {
  const int t = threadIdx.x;
  int v = (t < nb) ? bsum[t] : 0;
  const int lane = t & 63, wv = t >> 6;
  int s = v;
#pragma unroll
  for (int o = 1; o < 64; o <<= 1) {
    int u = __shfl_up(s, o);
    if (lane >= o) s += u;
  }
  __shared__ int wsum[2];
  if (lane == 63) wsum[wv] = s;
  __syncthreads();
  const int incl = ((wv == 1) ? wsum[0] : 0) + s;
  if (t < nb) bbase[t] = incl - v;
  if (t == 127) bbase[nb] = incl;
}

__global__ __launch_bounds__(256) void k_scan_c(
    const int* __restrict__ cnt, const int* __restrict__ bbase, int n, int nb,
    int* __restrict__ row, int* __restrict__ fill, float* __restrict__ inv) {
  int i = blockIdx.x * blockDim.x + threadIdx.x;
  if (i < n) {
    int v = row[i] + bbase[i >> 9];
    row[i] = v;
    fill[i] = v;
    int c = cnt[i];
    inv[i] = c > 0 ? 1.f / (float)c : 0.f;
  }
  if (i == 0) row[n] = bbase[nb];
}

// fill CSR incidence lists + direct neighbor lists (order arbitrary)
__global__ void k_fill(const int* __restrict__ nidx, const int* __restrict__ eidx,
                       int* __restrict__ fillN, int* __restrict__ fillE,
                       int* __restrict__ jlN, int* __restrict__ jlE,
                       int* __restrict__ elN, int* __restrict__ nlE) {
  int j = blockIdx.x * blockDim.x + threadIdx.x;
  if (j < NNZV) {
    int n = nidx[j], e = eidx[j];
    int p = atomicAdd(&fillN[n], 1);
    jlN[p] = j; elN[p] = e;
    int q = atomicAdd(&fillE[e], 1);
    jlE[q] = j; nlE[q] = n;
  }
}

// ---------------------------------------------------------------------------
// gather to edges: one wave per edge. p-loop unrolled x2 with loads grouped
// before FMAs to double memory-level parallelism on the idx->row chain.
__global__ __launch_bounds__(256) void k_gather_e(
    const int* __restrict__ rowE, const int* __restrict__ jlE,
    const int* __restrict__ nlE, const float* __restrict__ alpha,
    const float* __restrict__ xl, const float* __restrict__ Binv,
    float* __restrict__ msum) {
  int e = (blockIdx.x * blockDim.x + threadIdx.x) >> 6;
  int lane = threadIdx.x & 63;
  if (e >= N_EDGES) return;
  float acc[DSTALK];
#pragma unroll
  for (int r = 0; r < DSTALK; r++) acc[r] = 0.f;
  const int lo = rowE[e], hi = rowE[e + 1];
  int p = lo;
  for (; p + 1 < hi; p += 2) {
    const int j0 = jlE[p],     n0 = nlE[p];
    const int j1 = jlE[p + 1], n1 = nlE[p + 1];
    const float* __restrict__ xr0 = xl + (size_t)n0 * HD + lane;
    const float* __restrict__ xr1 = xl + (size_t)n1 * HD + lane;
    const float* __restrict__ ar0 = alpha + (size_t)j0 * DSTALK;
    const float* __restrict__ ar1 = alpha + (size_t)j1 * DSTALK;
    float v0[DSTALK], v1[DSTALK], a0[DSTALK], a1[DSTALK];
#pragma unroll
    for (int r = 0; r < DSTALK; r++) {
      v0[r] = xr0[r * HDIM];
      v1[r] = xr1[r * HDIM];
      a0[r] = ar0[r];
      a1[r] = ar1[r];
    }
#pragma unroll
    for (int r = 0; r < DSTALK; r++) acc[r] += a0[r] * v0[r] + a1[r] * v1[r];
  }
  if (p < hi) {
    const int j0 = jlE[p], n0 = nlE[p];
    const float* __restrict__ xr0 = xl + (size_t)n0 * HD + lane;
    const float* __restrict__ ar0 = alpha + (size_t)j0 * DSTALK;
#pragma unroll
    for (int r = 0; r < DSTALK; r++) acc[r] += ar0[r] * xr0[r * HDIM];
  }
  const float bv = Binv[e];
  float* __restrict__ mr = msum + (size_t)e * HD + lane;
#pragma unroll
  for (int r = 0; r < DSTALK; r++) mr[r * HDIM] = acc[r] * bv;
}

// gather back to nodes + bias + ELU epilogue: one wave per node. Same x2
// unroll with grouped loads.
__global__ __launch_bounds__(256) void k_gather_n(
    const int* __restrict__ rowN, const int* __restrict__ jlN,
    const int* __restrict__ elN, const float* __restrict__ alpha,
    const float* __restrict__ msum, const float* __restrict__ Dinv,
    const float* __restrict__ xl, const float* __restrict__ bias,
    float* __restrict__ outp) {
  int n = (blockIdx.x * blockDim.x + threadIdx.x) >> 6;
  int lane = threadIdx.x & 63;
  if (n >= N_NODES) return;
  float acc[DSTALK];
#pragma unroll
  for (int r = 0; r < DSTALK; r++) acc[r] = 0.f;
  const int lo = rowN[n], hi = rowN[n + 1];
  int p = lo;
  for (; p + 1 < hi; p += 2) {
    const int j0 = jlN[p],     e0 = elN[p];
    const int j1 = jlN[p + 1], e1 = elN[p + 1];
    const float* __restrict__ mr0 = msum + (size_t)e0 * HD + lane;
    const float* __restrict__ mr1 = msum + (size_t)e1 * HD + lane;
    const float* __restrict__ ar0 = alpha + (size_t)j0 * DSTALK;
    const float* __restrict__ ar1 = alpha + (size_t)j1 * DSTALK;
    float v0[DSTALK], v1[DSTALK], a0[DSTALK], a1[DSTALK];
#pragma unroll
    for (int r = 0; r < DSTALK; r++) {
      v0[r] = mr0[r * HDIM];
      v1[r] = mr1[r * HDIM];
      a0[r] = ar0[r];
      a1[r] = ar1[r];
    }
#pragma unroll
    for (int r = 0; r < DSTALK; r++) acc[r] += a0[r] * v0[r] + a1[r] * v1[r];
  }
  if (p < hi) {
    const int j0 = jlN[p], e0 = elN[p];
    const float* __restrict__ mr0 = msum + (size_t)e0 * HD + lane;
    const float* __restrict__ ar0 = alpha + (size_t)j0 * DSTALK;
#pragma unroll
    for (int r = 0; r < DSTALK; r++) acc[r] += ar0[r] * mr0[r * HDIM];
  }
  const float dv = Dinv[n];
  const float bb = bias[lane];
  const float* __restrict__ xr = xl + (size_t)n * HD + lane;
  float* __restrict__ orow = outp + (size_t)n * HD + lane;
#pragma unroll
  for (int r = 0; r < DSTALK; r++) {
    float v = xr[r * HDIM] + bb - dv * acc[r];
    orow[r * HDIM] = v > 0.f ? v : expm1f(v);
  }
}

// ---------------------------------------------------------------------------
extern "C" void kernel_launch(void* const* d_in, const int* in_sizes, int n_in,
                              void* d_out, int out_size, void* d_ws, size_t ws_size,
                              hipStream_t stream) {
  const float* x    = (const float*)d_in[0];
  const float* hea  = (const float*)d_in[1];
  const int*  nidx  = (const int*)d_in[2];
  const int*  eidx  = (const int*)d_in[3];
  // d_in[4], d_in[5] = node_types / hyperedge_types: unused by reference
  const float* W_lin = (const float*)d_in[6];
  const float* b_lin = (const float*)d_in[7];
  const float* ln_g  = (const float*)d_in[8];
  const float* ln_b  = (const float*)d_in[9];
  const float* W_sh  = (const float*)d_in[10];
  const float* b_sh  = (const float*)d_in[11];
  const float* W_c0  = (const float*)d_in[12];
  const float* b_c0  = (const float*)d_in[13];
  const float* W_c1  = (const float*)d_in[14];
  const float* b_c1  = (const float*)d_in[15];
  float* out = (float*)d_out;

  // workspace layout (f32), 256B aligned. Total ~105 MB.
  char* ws = (char*)d_ws;
  size_t off = 0;
  auto alloc = [&](size_t bytes) {
    size_t o = off;
    off = (off + bytes + 255) & ~(size_t)255;
    return o;
  };
  size_t o_xl0   = alloc((size_t)NROWS * HDIM * 4);               // 76.8 MB
  size_t o_msum  = alloc((size_t)EROWS * HDIM * 4);               // 15.36 MB
  size_t o_alpha = alloc((size_t)NNZV * DSTALK * 4);              // 6 MB
  size_t o_stats = alloc((size_t)(N_NODES + N_EDGES) * 8 * 4);    // 1.92 MB
  size_t o_jlN   = alloc((size_t)NNZV * 4);                       // 1 MB
  size_t o_jlE   = alloc((size_t)NNZV * 4);                       // 1 MB
  size_t o_elN   = alloc((size_t)NNZV * 4);                       // 1 MB
  size_t o_nlE   = alloc((size_t)NNZV * 4);                       // 1 MB
  size_t o_cntN  = alloc((size_t)N_NODES * 4);
  size_t o_cntE  = alloc((size_t)N_EDGES * 4);
  size_t o_rowN  = alloc((size_t)(N_NODES + 1) * 4);
  size_t o_rowE  = alloc((size_t)(N_EDGES + 1) * 4);
  size_t o_filN  = alloc((size_t)N_NODES * 4);
  size_t o_filE  = alloc((size_t)N_EDGES * 4);
  size_t o_Dinv  = alloc((size_t)N_NODES * 4);
  size_t o_Binv  = alloc((size_t)N_EDGES * 4);
  size_t o_bsN   = alloc((size_t)256 * 4);
  size_t o_bbN   = alloc((size_t)256 * 4);
  size_t o_bsE   = alloc((size_t)256 * 4);
  size_t o_bbE   = alloc((size_t)256 * 4);
  size_t o_WeffT = alloc((size_t)IN_CH * HD * 4);                 // 196 KB
  size_t o_Wm    = alloc((size_t)IN_CH * HDIM * 4);               // 32 KB
  size_t o_cm    = alloc((size_t)HDIM * 4);
  size_t o_c0    = alloc((size_t)HD * 4);
  size_t o_gwN   = alloc((size_t)64 * DSTALK * 4);
  size_t o_gwE   = alloc((size_t)64 * DSTALK * 4);
  size_t o_G     = alloc((size_t)DSTALK * 4);
  size_t o_K     = alloc((size_t)DSTALK * 4);
  size_t o_W1T   = alloc((size_t)HDIM * HDIM * 4);                // 16 KB

  float* xl0    = (float*)(ws + o_xl0);
  float* msum   = (float*)(ws + o_msum);
  float* alpha  = (float*)(ws + o_alpha);
  float* stats  = (float*)(ws + o_stats);
  int*   jlN    = (int*)(ws + o_jlN);
  int*   jlE    = (int*)(ws + o_jlE);
  int*   elN    = (int*)(ws + o_elN);
  int*   nlE    = (int*)(ws + o_nlE);
  int*   cntN   = (int*)(ws + o_cntN);
  int*   cntE   = (int*)(ws + o_cntE);
  int*   rowN   = (int*)(ws + o_rowN);
  int*   rowE   = (int*)(ws + o_rowE);
  int*   filN   = (int*)(ws + o_filN);
  int*   filE   = (int*)(ws + o_filE);
  float* Dinv   = (float*)(ws + o_Dinv);
  float* Binv   = (float*)(ws + o_Binv);
  int*   bsN    = (int*)(ws + o_bsN);
  int*   bbN    = (int*)(ws + o_bbN);
  int*   bsE    = (int*)(ws + o_bsE);
  int*   bbE    = (int*)(ws + o_bbE);
  float* W0effT = (float*)(ws + o_WeffT);
  float* Wm     = (float*)(ws + o_Wm);
  float* cm     = (float*)(ws + o_cm);
  float* c0     = (float*)(ws + o_c0);
  float* gwN    = (float*)(ws + o_gwN);
  float* gwE    = (float*)(ws + o_gwE);
  float* G      = (float*)(ws + o_G);
  float* K      = (float*)(ws + o_K);
  float* W1T    = (float*)(ws + o_W1T);

  const int NB_N = (N_NODES + 511) / 512;  // 98
  const int NB_E = (N_EDGES + 511) / 512;  // 20

  // 0. weight prep
  k_wefft<<<(IN_CH * HD + 255) / 256, 256, 0, stream>>>(W_lin, W_c0, W0effT);
  k_wsmall<<<(WS_END + 255) / 256, 256, 0, stream>>>(
      W_lin, b_lin, W_c0, W_c1, ln_g, ln_b, W_sh, b_sh,
      Wm, cm, c0, gwN, gwE, G, K, W1T);

  // 1. CSR build: counts -> parallel scans (+Dinv/Binv) -> fill
  hipMemsetAsync(ws + o_cntN, 0, (size_t)N_NODES * 4, stream);
  hipMemsetAsync(ws + o_cntE, 0, (size_t)N_EDGES * 4, stream);
  k_count<<<(NNZV + 255) / 256, 256, 0, stream>>>(nidx, eidx, cntN, cntE);
  k_scan_a<<<NB_N, 256, 0, stream>>>(cntN, N_NODES, rowN, bsN);
  k_scan_a<<<NB_E, 256, 0, stream>>>(cntE, N_EDGES, rowE, bsE);
  k_scan_b<<<1, 128, 0, stream>>>(bsN, NB_N, bbN);
  k_scan_b<<<1, 128, 0, stream>>>(bsE, NB_E, bbE);
  k_scan_c<<<(N_NODES + 255) / 256, 256, 0, stream>>>(cntN, bbN, N_NODES, NB_N,
                                                      rowN, filN, Dinv);
  k_scan_c<<<(N_EDGES + 255) / 256, 256, 0, stream>>>(cntE, bbE, N_EDGES, NB_E,
                                                      rowE, filE, Binv);
  k_fill<<<(NNZV + 255) / 256, 256, 0, stream>>>(nidx, eidx, filN, filE,
                                                 jlN, jlE, elN, nlE);

  // 2. fused stalk-mean + LN sufficient stats
  k_xa_stats<<<(N_NODES + N_EDGES + 63) / 64, 256, 0, stream>>>(
      x, hea, Wm, cm, gwN, gwE, stats);

  // 3. closed-form sheaf coefficients alpha [NNZ x 6]
  k_sheaf2<<<(NNZV + 255) / 256, 256, 0, stream>>>(nidx, eidx, stats, G, K, alpha);

  // 4. conv0: xl0 = xs@W0 (fused via W0effT); gather-diffusion; bias+ELU fused
  {
    dim3 g((N_NODES + 127) / 128, HD / 128);   // (391, 3)
    k_xl0<<<g, 256, 0, stream>>>(x, W0effT, c0, xl0);
  }
  k_gather_e<<<(N_EDGES + 3) / 4, 256, 0, stream>>>(rowE, jlE, nlE, alpha, xl0, Binv, msum);
  k_gather_n<<<(N_NODES + 3) / 4, 256, 0, stream>>>(rowN, jlN, elN, alpha, msum, Dinv,
                                                    xl0, b_c0, xl0);  // xl0 now holds h1

  // 5. conv1: xl1 = h1@W1 (in place); gather-diffusion; bias+ELU into d_out
  k_xw<<<(NROWS + 127) / 128, 256, 0, stream>>>(xl0, W1T, xl0);
  k_gather_e<<<(N_EDGES + 3) / 4, 256, 0, stream>>>(rowE, jlE, nlE, alpha, xl0, Binv, msum);
  k_gather_n<<<(N_NODES + 3) / 4, 256, 0, stream>>>(rowN, jlN, elN, alpha, msum, Dinv,
                                                    xl0, b_c1, out);

  (void)in_sizes; (void)n_in; (void)out_size; (void)ws_size;
}

// Round 8
// 653.103 us; speedup vs baseline: 1.1546x; 1.1546x over previous
//
#include <hip/hip_runtime.h>
#include <hip/hip_bf16.h>

// Problem constants (from reference)
#define N_NODES 50000
#define N_EDGES 10000
#define NNZV    250000
#define IN_CH   128
#define HDIM    64
#define DSTALK  6
#define HD      384   // HDIM * DSTALK
#define NROWS   (N_NODES * DSTALK)   // 300000
#define EROWS   (N_EDGES * DSTALK)   // 60000

// ---------------------------------------------------------------------------
// W-prep 1: W0effT[j][k] = sum_m W_lin[k][r*64+m] * W0[m][h]  (j=r*64+h)
// transposed [384][128] so the GEMM can vector-load along k.
__global__ __launch_bounds__(256) void k_wefft(
    const float* __restrict__ W_lin, const float* __restrict__ W0,
    float* __restrict__ W0effT) {
  int idx = blockIdx.x * blockDim.x + threadIdx.x;
  if (idx >= IN_CH * HD) return;
  int k = idx / HD, j = idx - k * HD;
  int r = j >> 6, h = j & 63;
  float s = 0.f;
#pragma unroll 8
  for (int m = 0; m < HDIM; m++)
    s += W_lin[k * HD + r * HDIM + m] * W0[m * HDIM + h];
  W0effT[(size_t)j * IN_CH + k] = s;
}

// W-prep 2: Wm, cm, c0 + sheaf tables gwN/gwE/G/K + W1T transpose
#define WS_BASE (IN_CH * HDIM + HD + HDIM)   // 8640
#define WS_END  (WS_BASE + 780 + HDIM * HDIM)
__global__ __launch_bounds__(256) void k_wsmall(
    const float* __restrict__ W_lin, const float* __restrict__ b_lin,
    const float* __restrict__ W0, const float* __restrict__ W1,
    const float* __restrict__ g, const float* __restrict__ bln,
    const float* __restrict__ Ws, const float* __restrict__ bs,
    float* __restrict__ Wm, float* __restrict__ cm, float* __restrict__ c0,
    float* __restrict__ gwN, float* __restrict__ gwE,
    float* __restrict__ G, float* __restrict__ K, float* __restrict__ W1T) {
  int idx = blockIdx.x * blockDim.x + threadIdx.x;
  if (idx < IN_CH * HDIM) {            // Wm
    int k = idx >> 6, h = idx & 63;
    float s = 0.f;
#pragma unroll
    for (int r = 0; r < DSTALK; r++) s += W_lin[k * HD + r * HDIM + h];
    Wm[idx] = s * (1.f / 6.f);
  } else if (idx < IN_CH * HDIM + HD) {  // c0
    int j = idx - IN_CH * HDIM;
    int r = j >> 6, h = j & 63;
    float s = 0.f;
#pragma unroll 8
    for (int m = 0; m < HDIM; m++) s += b_lin[r * HDIM + m] * W0[m * HDIM + h];
    c0[j] = s;
  } else if (idx < WS_BASE) {  // cm
    int h = idx - IN_CH * HDIM - HD;
    float s = 0.f;
#pragma unroll
    for (int r = 0; r < DSTALK; r++) s += b_lin[r * HDIM + h];
    cm[h] = s * (1.f / 6.f);
  } else if (idx < WS_BASE + 384) {      // gwN
    int i = idx - WS_BASE;
    int h = i / 6, r = i - h * 6;
    gwN[i] = g[h] * Ws[h * DSTALK + r];
  } else if (idx < WS_BASE + 768) {      // gwE
    int i = idx - WS_BASE - 384;
    int h = i / 6, r = i - h * 6;
    gwE[i] = g[64 + h] * Ws[(64 + h) * DSTALK + r];
  } else if (idx < WS_BASE + 774) {      // G
    int r = idx - WS_BASE - 768;
    float s = 0.f;
    for (int i = 0; i < 2 * HDIM; i++) s += g[i] * Ws[i * DSTALK + r];
    G[r] = s;
  } else if (idx < WS_BASE + 780) {      // K
    int r = idx - WS_BASE - 774;
    float s = 0.f;
    for (int i = 0; i < 2 * HDIM; i++) s += bln[i] * Ws[i * DSTALK + r];
    K[r] = s + bs[r];
  } else if (idx < WS_END) {             // W1T[c][k] = W1[k][c]
    int i = idx - WS_BASE - 780;
    int c = i >> 6, k = i & 63;
    W1T[c * HDIM + k] = W1[k * HDIM + c];
  }
}

// ---------------------------------------------------------------------------
// Fused: row features xa = [x;hea]@Wm + cm (LDS only) -> per-row stats
__global__ __launch_bounds__(256) void k_xa_stats(
    const float* __restrict__ x, const float* __restrict__ ea,
    const float* __restrict__ Wm, const float* __restrict__ cm,
    const float* __restrict__ gwN, const float* __restrict__ gwE,
    float* __restrict__ stats) {
  __shared__ float lx[64][IN_CH];      // 32 KB input tile
  __shared__ float ox[64][HDIM + 1];   // 16.6 KB feature tile (padded)
  __shared__ float lgw[2][64 * DSTALK];
  const int row0 = blockIdx.x * 64;
  const int tid = threadIdx.x;
  for (int i = tid; i < 2 * 64 * DSTALK; i += 256) {
    int which = i / 384, k = i - which * 384;
    lgw[which][k] = which ? gwE[k] : gwN[k];
  }
  for (int i = tid; i < 64 * IN_CH; i += 256) {
    int r = i >> 7, k = i & 127;
    int row = row0 + r;
    float v = 0.f;
    if (row < N_NODES) v = x[row * IN_CH + k];
    else if (row < N_NODES + N_EDGES) v = ea[(row - N_NODES) * IN_CH + k];
    lx[r][k] = v;
  }
  __syncthreads();
  const int col = tid & 63, rg = tid >> 6;  // 4 groups x 16 rows
  float acc[16];
#pragma unroll
  for (int i = 0; i < 16; i++) acc[i] = 0.f;
  for (int k = 0; k < IN_CH; k++) {
    float w = Wm[k * HDIM + col];
#pragma unroll
    for (int i = 0; i < 16; i++) acc[i] += lx[rg * 16 + i][k] * w;
  }
  const float c = cm[col];
#pragma unroll
  for (int i = 0; i < 16; i++) ox[rg * 16 + i][col] = acc[i] + c;
  __syncthreads();
  // 512 reduction tasks: (row, stat). stat: 0=s1, 1=s2, 2..7=p[r]
  for (int t = tid; t < 512; t += 256) {
    int row = t >> 3, st = t & 7;
    int grow = row0 + row;
    if (grow >= N_NODES + N_EDGES) continue;
    const float* __restrict__ gw = (grow >= N_NODES) ? lgw[1] : lgw[0];
    float s = 0.f;
    if (st == 0) {
#pragma unroll 8
      for (int h = 0; h < HDIM; h++) s += ox[row][h];
    } else if (st == 1) {
#pragma unroll 8
      for (int h = 0; h < HDIM; h++) { float v = ox[row][h]; s += v * v; }
    } else {
      int r = st - 2;
#pragma unroll 8
      for (int h = 0; h < HDIM; h++) s += ox[row][h] * gw[h * DSTALK + r];
    }
    stats[(size_t)grow * 8 + st] = s;
  }
}

// ---------------------------------------------------------------------------
// Register-tiled fp32 GEMM: xl0[row][col] = x[row][:] . W0effT[col][:] + c0
// 128x128 tile per block, 8x8 per thread, BK=32, DIRECT staging.
// STABLE OPTIMUM of this structure (95.6us, VGPR 80, zero spill). Ledger:
// - register prefetch (r1-r2): spills ~40MB scratch regardless of VGPR cap
// - full kq unroll (r5): acc spills inside inner loop, 4.4GB HBM traffic
// - A direct from global, B-only LDS (r7): VMEM latency exposed, 161us
// -> A and B both staged to LDS, kq at unroll 1. DO NOT PERTURB.
__global__ __launch_bounds__(256, 2) void k_xl0(
    const float* __restrict__ x, const float* __restrict__ W0effT,
    const float* __restrict__ c0, float* __restrict__ xl0) {
  __shared__ float4 aS[8][129];   // [kq][row], pad residue 4 -> 0-conflict (measured)
  __shared__ float4 bS[8][129];   // [kq][col]
  const int tid = threadIdx.x;
  const int row0 = blockIdx.x * 128;
  const int col0 = blockIdx.y * 128;
  const int tc = tid & 15, tr = tid >> 4;   // 16x16 thread grid
  float acc[8][8];
#pragma unroll
  for (int i = 0; i < 8; i++)
#pragma unroll
    for (int j = 0; j < 8; j++) acc[i][j] = 0.f;

#pragma unroll 1
  for (int kc = 0; kc < 4; kc++) {
    if (kc) __syncthreads();
    // stage A: 1024 float4 (4/thread), direct to LDS
#pragma unroll
    for (int i = 0; i < 4; i++) {
      int fidx = tid + (i << 8);         // 0..1023
      int kq = fidx & 7, row = fidx >> 3;
      int gk = kc * 32 + kq * 4;
      int grow = row0 + row;
      aS[kq][row] = (grow < N_NODES)
                        ? *(const float4*)(x + (size_t)grow * IN_CH + gk)
                        : make_float4(0.f, 0.f, 0.f, 0.f);
    }
    // stage B: 1024 float4 (4/thread)
#pragma unroll
    for (int i = 0; i < 4; i++) {
      int fidx = tid + (i << 8);         // 0..1023
      int kq = fidx & 7, col = fidx >> 3;
      int gk = kc * 32 + kq * 4;
      bS[kq][col] =
          *(const float4*)(W0effT + (size_t)(col0 + col) * IN_CH + gk);
    }
    __syncthreads();
#pragma unroll 1
    for (int kq = 0; kq < 8; kq++) {
      float4 b[8];
#pragma unroll
      for (int j = 0; j < 8; j++) b[j] = bS[kq][tc + (j << 4)];
#pragma unroll
      for (int i = 0; i < 8; i++) {
        float4 a = aS[kq][tr + (i << 4)];
#pragma unroll
        for (int j = 0; j < 8; j++)
          acc[i][j] += a.x * b[j].x + a.y * b[j].y + a.z * b[j].z + a.w * b[j].w;
      }
    }
  }

  float cc[8];
#pragma unroll
  for (int j = 0; j < 8; j++) cc[j] = c0[col0 + tc + (j << 4)];
#pragma unroll
  for (int i = 0; i < 8; i++) {
    int row = row0 + tr + (i << 4);
    if (row >= N_NODES) continue;
    float* __restrict__ orow = xl0 + (size_t)row * HD + col0;
#pragma unroll
    for (int j = 0; j < 8; j++) {
      orow[tc + (j << 4)] = acc[i][j] + cc[j];
    }
  }
}

// ---------------------------------------------------------------------------
// Register-tiled fp32 GEMM: xl = xin @ W1 (K=64, N=64). In-place safe (all
// of a block's reads complete before its epilogue writes; rows are disjoint
// across blocks). 128-row x 64-col tile, 8x4 per thread, BK=32. Round-4
// proven form (see k_xl0 ledger -- same rules apply).
__global__ __launch_bounds__(256) void k_xw(
    const float* __restrict__ xin, const float* __restrict__ W1T,
    float* __restrict__ xl) {
  __shared__ float4 aS[8][129];   // [kq][row] rows=128
  __shared__ float4 bS[8][65];    // [kq][col] cols=64
  const int tid = threadIdx.x;
  const int row0 = blockIdx.x * 128;
  const int tc = tid & 15, tr = tid >> 4;
  float acc[8][4];
#pragma unroll
  for (int i = 0; i < 8; i++)
#pragma unroll
    for (int j = 0; j < 4; j++) acc[i][j] = 0.f;

#pragma unroll 1
  for (int kc = 0; kc < 2; kc++) {
    if (kc) __syncthreads();
    // stage A: 1024 float4 (4/thread)
#pragma unroll
    for (int i = 0; i < 4; i++) {
      int fidx = tid + (i << 8);         // 0..1023
      int kq = fidx & 7, row = fidx >> 3;
      int gk = kc * 32 + kq * 4;
      int grow = row0 + row;
      aS[kq][row] = (grow < NROWS)
                        ? *(const float4*)(xin + (size_t)grow * HDIM + gk)
                        : make_float4(0.f, 0.f, 0.f, 0.f);
    }
    // stage B: 512 float4 (2/thread)
#pragma unroll
    for (int i = 0; i < 2; i++) {
      int fidx = tid + (i << 8);         // 0..511
      int kq = fidx & 7, col = fidx >> 3;
      int gk = kc * 32 + kq * 4;
      bS[kq][col] = *(const float4*)(W1T + col * HDIM + gk);
    }
    __syncthreads();
#pragma unroll 1
    for (int kq = 0; kq < 8; kq++) {
      float4 b[4];
#pragma unroll
      for (int j = 0; j < 4; j++) b[j] = bS[kq][tc + (j << 4)];
#pragma unroll
      for (int i = 0; i < 8; i++) {
        float4 a = aS[kq][tr + (i << 4)];
#pragma unroll
        for (int j = 0; j < 4; j++)
          acc[i][j] += a.x * b[j].x + a.y * b[j].y + a.z * b[j].z + a.w * b[j].w;
      }
    }
  }
#pragma unroll
  for (int i = 0; i < 8; i++) {
    int row = row0 + tr + (i << 4);
    if (row >= NROWS) continue;
#pragma unroll
    for (int j = 0; j < 4; j++) {
      int col = tc + (j << 4);
      xl[(size_t)row * HDIM + col] = acc[i][j];
    }
  }
}

// ---------------------------------------------------------------------------
// closed-form sheaf coefficients: one THREAD per incidence
__global__ __launch_bounds__(256) void k_sheaf2(
    const int* __restrict__ nidx, const int* __restrict__ eidx,
    const float* __restrict__ stats,
    const float* __restrict__ G, const float* __restrict__ K,
    float* __restrict__ alpha) {
  int j = blockIdx.x * blockDim.x + threadIdx.x;
  if (j >= NNZV) return;
  int n = nidx[j], e = eidx[j];
  const float4* __restrict__ sn = (const float4*)(stats + (size_t)n * 8);
  const float4* __restrict__ se = (const float4*)(stats + ((size_t)(N_NODES + e)) * 8);
  float4 a0 = sn[0], a1 = sn[1];
  float4 b0 = se[0], b1 = se[1];
  float mu = (a0.x + b0.x) * (1.f / 128.f);
  float var = (a0.y + b0.y) * (1.f / 128.f) - mu * mu;
  float rs = rsqrtf(var + 1e-5f);
  float p[DSTALK] = {a0.z + b0.z, a0.w + b0.w, a1.x + b1.x,
                     a1.y + b1.y, a1.z + b1.z, a1.w + b1.w};
#pragma unroll
  for (int r = 0; r < DSTALK; r++) {
    float z = rs * (p[r] - mu * G[r]) + K[r];
    alpha[(size_t)j * DSTALK + r] = 1.f / (1.f + expf(-z));
  }
}

// ---------------------------------------------------------------------------
// degree counts
__global__ void k_count(const int* __restrict__ nidx, const int* __restrict__ eidx,
                        int* __restrict__ cntN, int* __restrict__ cntE) {
  int j = blockIdx.x * blockDim.x + threadIdx.x;
  if (j < NNZV) {
    atomicAdd(&cntN[nidx[j]], 1);
    atomicAdd(&cntE[eidx[j]], 1);
  }
}

// ---------------------------------------------------------------------------
// Multi-block exclusive scan, 512 elements/block.
__global__ __launch_bounds__(256) void k_scan_a(
    const int* __restrict__ cnt, int n, int* __restrict__ row,
    int* __restrict__ bsum) {
  const int b = blockIdx.x, t = threadIdx.x;
  const int i0 = b * 512 + 2 * t, i1 = i0 + 1;
  int c0 = (i0 < n) ? cnt[i0] : 0;
  int c1 = (i1 < n) ? cnt[i1] : 0;
  int ts = c0 + c1;
  const int lane = t & 63, wv = t >> 6;
  int s = ts;
#pragma unroll
  for (int o = 1; o < 64; o <<= 1) {
    int v = __shfl_up(s, o);
    if (lane >= o) s += v;
  }
  __shared__ int wsum[4];
  if (lane == 63) wsum[wv] = s;
  __syncthreads();
  int wbase = 0;
#pragma unroll
  for (int wprev = 0; wprev < 3; wprev++)
    if (wprev < wv) wbase += wsum[wprev];
  const int incl = wbase + s;
  const int excl = incl - ts;
  if (i0 < n) row[i0] = excl;
  if (i1 < n) row[i1] = excl + c0;
  if (t == 255) bsum[b] = incl;
}

__global__ __launch_bounds__(128) void k_scan_b(
    const int* __restrict__ bsum, int nb, int* __restrict__ bbase) {
  const int t = threadIdx.x;
  int v = (t < nb) ? bsum[t] : 0;
  const int lane = t & 63, wv = t >> 6;
  int s = v;
#pragma unroll
  for (int o = 1; o < 64; o <<= 1) {
    int u = __shfl_up(s, o);
    if (lane >= o) s += u;
  }
  __shared__ int wsum[2];
  if (lane == 63) wsum[wv] = s;
  __syncthreads();
  const int incl = ((wv == 1) ? wsum[0] : 0) + s;
  if (t < nb) bbase[t] = incl - v;
  if (t == 127) bbase[nb] = incl;
}

__global__ __launch_bounds__(256) void k_scan_c(
    const int* __restrict__ cnt, const int* __restrict__ bbase, int n, int nb,
    int* __restrict__ row, int* __restrict__ fill, float* __restrict__ inv) {
  int i = blockIdx.x * blockDim.x + threadIdx.x;
  if (i < n) {
    int v = row[i] + bbase[i >> 9];
    row[i] = v;
    fill[i] = v;
    int c = cnt[i];
    inv[i] = c > 0 ? 1.f / (float)c : 0.f;
  }
  if (i == 0) row[n] = bbase[nb];
}

// fill CSR incidence lists + direct neighbor lists (order arbitrary)
__global__ void k_fill(const int* __restrict__ nidx, const int* __restrict__ eidx,
                       int* __restrict__ fillN, int* __restrict__ fillE,
                       int* __restrict__ jlN, int* __restrict__ jlE,
                       int* __restrict__ elN, int* __restrict__ nlE) {
  int j = blockIdx.x * blockDim.x + threadIdx.x;
  if (j < NNZV) {
    int n = nidx[j], e = eidx[j];
    int p = atomicAdd(&fillN[n], 1);
    jlN[p] = j; elN[p] = e;
    int q = atomicAdd(&fillE[e], 1);
    jlE[q] = j; nlE[q] = n;
  }
}

// ---------------------------------------------------------------------------
// gather to edges: one wave per edge. p-loop unrolled x4 (was x2, +16us over
// baseline) with all idx+row loads grouped before FMAs: probes whether the
// gathers are idx->row latency-bound (x4 helps) or L3/HBM BW-bound (neutral).
__global__ __launch_bounds__(256) void k_gather_e(
    const int* __restrict__ rowE, const int* __restrict__ jlE,
    const int* __restrict__ nlE, const float* __restrict__ alpha,
    const float* __restrict__ xl, const float* __restrict__ Binv,
    float* __restrict__ msum) {
  int e = (blockIdx.x * blockDim.x + threadIdx.x) >> 6;
  int lane = threadIdx.x & 63;
  if (e >= N_EDGES) return;
  float acc[DSTALK];
#pragma unroll
  for (int r = 0; r < DSTALK; r++) acc[r] = 0.f;
  const int lo = rowE[e], hi = rowE[e + 1];
  int p = lo;
  for (; p + 3 < hi; p += 4) {
    int jj[4], nn[4];
#pragma unroll
    for (int u = 0; u < 4; u++) { jj[u] = jlE[p + u]; nn[u] = nlE[p + u]; }
    float v[4][DSTALK], a[4][DSTALK];
#pragma unroll
    for (int u = 0; u < 4; u++) {
      const float* __restrict__ xr = xl + (size_t)nn[u] * HD + lane;
      const float* __restrict__ ar = alpha + (size_t)jj[u] * DSTALK;
#pragma unroll
      for (int r = 0; r < DSTALK; r++) { v[u][r] = xr[r * HDIM]; a[u][r] = ar[r]; }
    }
#pragma unroll
    for (int r = 0; r < DSTALK; r++)
      acc[r] += a[0][r] * v[0][r] + a[1][r] * v[1][r] +
                a[2][r] * v[2][r] + a[3][r] * v[3][r];
  }
  for (; p < hi; p++) {
    const int j0 = jlE[p], n0 = nlE[p];
    const float* __restrict__ xr0 = xl + (size_t)n0 * HD + lane;
    const float* __restrict__ ar0 = alpha + (size_t)j0 * DSTALK;
#pragma unroll
    for (int r = 0; r < DSTALK; r++) acc[r] += ar0[r] * xr0[r * HDIM];
  }
  const float bv = Binv[e];
  float* __restrict__ mr = msum + (size_t)e * HD + lane;
#pragma unroll
  for (int r = 0; r < DSTALK; r++) mr[r * HDIM] = acc[r] * bv;
}

// gather back to nodes + bias + ELU epilogue: one wave per node. Same x4
// unroll with grouped loads.
__global__ __launch_bounds__(256) void k_gather_n(
    const int* __restrict__ rowN, const int* __restrict__ jlN,
    const int* __restrict__ elN, const float* __restrict__ alpha,
    const float* __restrict__ msum, const float* __restrict__ Dinv,
    const float* __restrict__ xl, const float* __restrict__ bias,
    float* __restrict__ outp) {
  int n = (blockIdx.x * blockDim.x + threadIdx.x) >> 6;
  int lane = threadIdx.x & 63;
  if (n >= N_NODES) return;
  float acc[DSTALK];
#pragma unroll
  for (int r = 0; r < DSTALK; r++) acc[r] = 0.f;
  const int lo = rowN[n], hi = rowN[n + 1];
  int p = lo;
  for (; p + 3 < hi; p += 4) {
    int jj[4], ee[4];
#pragma unroll
    for (int u = 0; u < 4; u++) { jj[u] = jlN[p + u]; ee[u] = elN[p + u]; }
    float v[4][DSTALK], a[4][DSTALK];
#pragma unroll
    for (int u = 0; u < 4; u++) {
      const float* __restrict__ mr = msum + (size_t)ee[u] * HD + lane;
      const float* __restrict__ ar = alpha + (size_t)jj[u] * DSTALK;
#pragma unroll
      for (int r = 0; r < DSTALK; r++) { v[u][r] = mr[r * HDIM]; a[u][r] = ar[r]; }
    }
#pragma unroll
    for (int r = 0; r < DSTALK; r++)
      acc[r] += a[0][r] * v[0][r] + a[1][r] * v[1][r] +
                a[2][r] * v[2][r] + a[3][r] * v[3][r];
  }
  for (; p < hi; p++) {
    const int j0 = jlN[p], e0 = elN[p];
    const float* __restrict__ mr0 = msum + (size_t)e0 * HD + lane;
    const float* __restrict__ ar0 = alpha + (size_t)j0 * DSTALK;
#pragma unroll
    for (int r = 0; r < DSTALK; r++) acc[r] += ar0[r] * mr0[r * HDIM];
  }
  const float dv = Dinv[n];
  const float bb = bias[lane];
  const float* __restrict__ xr = xl + (size_t)n * HD + lane;
  float* __restrict__ orow = outp + (size_t)n * HD + lane;
#pragma unroll
  for (int r = 0; r < DSTALK; r++) {
    float v = xr[r * HDIM] + bb - dv * acc[r];
    orow[r * HDIM] = v > 0.f ? v : expm1f(v);
  }
}

// ---------------------------------------------------------------------------
extern "C" void kernel_launch(void* const* d_in, const int* in_sizes, int n_in,
                              void* d_out, int out_size, void* d_ws, size_t ws_size,
                              hipStream_t stream) {
  const float* x    = (const float*)d_in[0];
  const float* hea  = (const float*)d_in[1];
  const int*  nidx  = (const int*)d_in[2];
  const int*  eidx  = (const int*)d_in[3];
  // d_in[4], d_in[5] = node_types / hyperedge_types: unused by reference
  const float* W_lin = (const float*)d_in[6];
  const float* b_lin = (const float*)d_in[7];
  const float* ln_g  = (const float*)d_in[8];
  const float* ln_b  = (const float*)d_in[9];
  const float* W_sh  = (const float*)d_in[10];
  const float* b_sh  = (const float*)d_in[11];
  const float* W_c0  = (const float*)d_in[12];
  const float* b_c0  = (const float*)d_in[13];
  const float* W_c1  = (const float*)d_in[14];
  const float* b_c1  = (const float*)d_in[15];
  float* out = (float*)d_out;

  // workspace layout (f32), 256B aligned. Total ~105 MB.
  char* ws = (char*)d_ws;
  size_t off = 0;
  auto alloc = [&](size_t bytes) {
    size_t o = off;
    off = (off + bytes + 255) & ~(size_t)255;
    return o;
  };
  size_t o_xl0   = alloc((size_t)NROWS * HDIM * 4);               // 76.8 MB
  size_t o_msum  = alloc((size_t)EROWS * HDIM * 4);               // 15.36 MB
  size_t o_alpha = alloc((size_t)NNZV * DSTALK * 4);              // 6 MB
  size_t o_stats = alloc((size_t)(N_NODES + N_EDGES) * 8 * 4);    // 1.92 MB
  size_t o_jlN   = alloc((size_t)NNZV * 4);                       // 1 MB
  size_t o_jlE   = alloc((size_t)NNZV * 4);                       // 1 MB
  size_t o_elN   = alloc((size_t)NNZV * 4);                       // 1 MB
  size_t o_nlE   = alloc((size_t)NNZV * 4);                       // 1 MB
  size_t o_cntN  = alloc((size_t)N_NODES * 4);
  size_t o_cntE  = alloc((size_t)N_EDGES * 4);
  size_t o_rowN  = alloc((size_t)(N_NODES + 1) * 4);
  size_t o_rowE  = alloc((size_t)(N_EDGES + 1) * 4);
  size_t o_filN  = alloc((size_t)N_NODES * 4);
  size_t o_filE  = alloc((size_t)N_EDGES * 4);
  size_t o_Dinv  = alloc((size_t)N_NODES * 4);
  size_t o_Binv  = alloc((size_t)N_EDGES * 4);
  size_t o_bsN   = alloc((size_t)256 * 4);
  size_t o_bbN   = alloc((size_t)256 * 4);
  size_t o_bsE   = alloc((size_t)256 * 4);
  size_t o_bbE   = alloc((size_t)256 * 4);
  size_t o_WeffT = alloc((size_t)IN_CH * HD * 4);                 // 196 KB
  size_t o_Wm    = alloc((size_t)IN_CH * HDIM * 4);               // 32 KB
  size_t o_cm    = alloc((size_t)HDIM * 4);
  size_t o_c0    = alloc((size_t)HD * 4);
  size_t o_gwN   = alloc((size_t)64 * DSTALK * 4);
  size_t o_gwE   = alloc((size_t)64 * DSTALK * 4);
  size_t o_G     = alloc((size_t)DSTALK * 4);
  size_t o_K     = alloc((size_t)DSTALK * 4);
  size_t o_W1T   = alloc((size_t)HDIM * HDIM * 4);                // 16 KB

  float* xl0    = (float*)(ws + o_xl0);
  float* msum   = (float*)(ws + o_msum);
  float* alpha  = (float*)(ws + o_alpha);
  float* stats  = (float*)(ws + o_stats);
  int*   jlN    = (int*)(ws + o_jlN);
  int*   jlE    = (int*)(ws + o_jlE);
  int*   elN    = (int*)(ws + o_elN);
  int*   nlE    = (int*)(ws + o_nlE);
  int*   cntN   = (int*)(ws + o_cntN);
  int*   cntE   = (int*)(ws + o_cntE);
  int*   rowN   = (int*)(ws + o_rowN);
  int*   rowE   = (int*)(ws + o_rowE);
  int*   filN   = (int*)(ws + o_filN);
  int*   filE   = (int*)(ws + o_filE);
  float* Dinv   = (float*)(ws + o_Dinv);
  float* Binv   = (float*)(ws + o_Binv);
  int*   bsN    = (int*)(ws + o_bsN);
  int*   bbN    = (int*)(ws + o_bbN);
  int*   bsE    = (int*)(ws + o_bsE);
  int*   bbE    = (int*)(ws + o_bbE);
  float* W0effT = (float*)(ws + o_WeffT);
  float* Wm     = (float*)(ws + o_Wm);
  float* cm     = (float*)(ws + o_cm);
  float* c0     = (float*)(ws + o_c0);
  float* gwN    = (float*)(ws + o_gwN);
  float* gwE    = (float*)(ws + o_gwE);
  float* G      = (float*)(ws + o_G);
  float* K      = (float*)(ws + o_K);
  float* W1T    = (float*)(ws + o_W1T);

  const int NB_N = (N_NODES + 511) / 512;  // 98
  const int NB_E = (N_EDGES + 511) / 512;  // 20

  // 0. weight prep
  k_wefft<<<(IN_CH * HD + 255) / 256, 256, 0, stream>>>(W_lin, W_c0, W0effT);
  k_wsmall<<<(WS_END + 255) / 256, 256, 0, stream>>>(
      W_lin, b_lin, W_c0, W_c1, ln_g, ln_b, W_sh, b_sh,
      Wm, cm, c0, gwN, gwE, G, K, W1T);

  // 1. CSR build: counts -> parallel scans (+Dinv/Binv) -> fill
  hipMemsetAsync(ws + o_cntN, 0, (size_t)N_NODES * 4, stream);
  hipMemsetAsync(ws + o_cntE, 0, (size_t)N_EDGES * 4, stream);
  k_count<<<(NNZV + 255) / 256, 256, 0, stream>>>(nidx, eidx, cntN, cntE);
  k_scan_a<<<NB_N, 256, 0, stream>>>(cntN, N_NODES, rowN, bsN);
  k_scan_a<<<NB_E, 256, 0, stream>>>(cntE, N_EDGES, rowE, bsE);
  k_scan_b<<<1, 128, 0, stream>>>(bsN, NB_N, bbN);
  k_scan_b<<<1, 128, 0, stream>>>(bsE, NB_E, bbE);
  k_scan_c<<<(N_NODES + 255) / 256, 256, 0, stream>>>(cntN, bbN, N_NODES, NB_N,
                                                      rowN, filN, Dinv);
  k_scan_c<<<(N_EDGES + 255) / 256, 256, 0, stream>>>(cntE, bbE, N_EDGES, NB_E,
                                                      rowE, filE, Binv);
  k_fill<<<(NNZV + 255) / 256, 256, 0, stream>>>(nidx, eidx, filN, filE,
                                                 jlN, jlE, elN, nlE);

  // 2. fused stalk-mean + LN sufficient stats
  k_xa_stats<<<(N_NODES + N_EDGES + 63) / 64, 256, 0, stream>>>(
      x, hea, Wm, cm, gwN, gwE, stats);

  // 3. closed-form sheaf coefficients alpha [NNZ x 6]
  k_sheaf2<<<(NNZV + 255) / 256, 256, 0, stream>>>(nidx, eidx, stats, G, K, alpha);

  // 4. conv0: xl0 = xs@W0 (fused via W0effT); gather-diffusion; bias+ELU fused
  {
    dim3 g((N_NODES + 127) / 128, HD / 128);   // (391, 3)
    k_xl0<<<g, 256, 0, stream>>>(x, W0effT, c0, xl0);
  }
  k_gather_e<<<(N_EDGES + 3) / 4, 256, 0, stream>>>(rowE, jlE, nlE, alpha, xl0, Binv, msum);
  k_gather_n<<<(N_NODES + 3) / 4, 256, 0, stream>>>(rowN, jlN, elN, alpha, msum, Dinv,
                                                    xl0, b_c0, xl0);  // xl0 now holds h1

  // 5. conv1: xl1 = h1@W1 (in place); gather-diffusion; bias+ELU into d_out
  k_xw<<<(NROWS + 127) / 128, 256, 0, stream>>>(xl0, W1T, xl0);
  k_gather_e<<<(N_EDGES + 3) / 4, 256, 0, stream>>>(rowE, jlE, nlE, alpha, xl0, Binv, msum);
  k_gather_n<<<(N_NODES + 3) / 4, 256, 0, stream>>>(rowN, jlN, elN, alpha, msum, Dinv,
                                                    xl0, b_c1, out);

  (void)in_sizes; (void)n_in; (void)out_size; (void)ws_size;
}

// Round 9
// 652.614 us; speedup vs baseline: 1.1555x; 1.0007x over previous
//
#include <hip/hip_runtime.h>
#include <hip/hip_bf16.h>

// Problem constants (from reference)
#define N_NODES 50000
#define N_EDGES 10000
#define NNZV    250000
#define IN_CH   128
#define HDIM    64
#define DSTALK  6
#define HD      384   // HDIM * DSTALK
#define NROWS   (N_NODES * DSTALK)   // 300000
#define EROWS   (N_EDGES * DSTALK)   // 60000

// ---------------------------------------------------------------------------
// W-prep 1: W0effT[j][k] = sum_m W_lin[k][r*64+m] * W0[m][h]  (j=r*64+h)
// transposed [384][128] so the GEMM can vector-load along k.
__global__ __launch_bounds__(256) void k_wefft(
    const float* __restrict__ W_lin, const float* __restrict__ W0,
    float* __restrict__ W0effT) {
  int idx = blockIdx.x * blockDim.x + threadIdx.x;
  if (idx >= IN_CH * HD) return;
  int k = idx / HD, j = idx - k * HD;
  int r = j >> 6, h = j & 63;
  float s = 0.f;
#pragma unroll 8
  for (int m = 0; m < HDIM; m++)
    s += W_lin[k * HD + r * HDIM + m] * W0[m * HDIM + h];
  W0effT[(size_t)j * IN_CH + k] = s;
}

// W-prep 2: Wm, cm, c0 + sheaf tables gwN/gwE/G/K + W1T transpose
#define WS_BASE (IN_CH * HDIM + HD + HDIM)   // 8640
#define WS_END  (WS_BASE + 780 + HDIM * HDIM)
__global__ __launch_bounds__(256) void k_wsmall(
    const float* __restrict__ W_lin, const float* __restrict__ b_lin,
    const float* __restrict__ W0, const float* __restrict__ W1,
    const float* __restrict__ g, const float* __restrict__ bln,
    const float* __restrict__ Ws, const float* __restrict__ bs,
    float* __restrict__ Wm, float* __restrict__ cm, float* __restrict__ c0,
    float* __restrict__ gwN, float* __restrict__ gwE,
    float* __restrict__ G, float* __restrict__ K, float* __restrict__ W1T) {
  int idx = blockIdx.x * blockDim.x + threadIdx.x;
  if (idx < IN_CH * HDIM) {            // Wm
    int k = idx >> 6, h = idx & 63;
    float s = 0.f;
#pragma unroll
    for (int r = 0; r < DSTALK; r++) s += W_lin[k * HD + r * HDIM + h];
    Wm[idx] = s * (1.f / 6.f);
  } else if (idx < IN_CH * HDIM + HD) {  // c0
    int j = idx - IN_CH * HDIM;
    int r = j >> 6, h = j & 63;
    float s = 0.f;
#pragma unroll 8
    for (int m = 0; m < HDIM; m++) s += b_lin[r * HDIM + m] * W0[m * HDIM + h];
    c0[j] = s;
  } else if (idx < WS_BASE) {  // cm
    int h = idx - IN_CH * HDIM - HD;
    float s = 0.f;
#pragma unroll
    for (int r = 0; r < DSTALK; r++) s += b_lin[r * HDIM + h];
    cm[h] = s * (1.f / 6.f);
  } else if (idx < WS_BASE + 384) {      // gwN
    int i = idx - WS_BASE;
    int h = i / 6, r = i - h * 6;
    gwN[i] = g[h] * Ws[h * DSTALK + r];
  } else if (idx < WS_BASE + 768) {      // gwE
    int i = idx - WS_BASE - 384;
    int h = i / 6, r = i - h * 6;
    gwE[i] = g[64 + h] * Ws[(64 + h) * DSTALK + r];
  } else if (idx < WS_BASE + 774) {      // G
    int r = idx - WS_BASE - 768;
    float s = 0.f;
    for (int i = 0; i < 2 * HDIM; i++) s += g[i] * Ws[i * DSTALK + r];
    G[r] = s;
  } else if (idx < WS_BASE + 780) {      // K
    int r = idx - WS_BASE - 774;
    float s = 0.f;
    for (int i = 0; i < 2 * HDIM; i++) s += bln[i] * Ws[i * DSTALK + r];
    K[r] = s + bs[r];
  } else if (idx < WS_END) {             // W1T[c][k] = W1[k][c]
    int i = idx - WS_BASE - 780;
    int c = i >> 6, k = i & 63;
    W1T[c * HDIM + k] = W1[k * HDIM + c];
  }
}

// ---------------------------------------------------------------------------
// Fused: row features xa = [x;hea]@Wm + cm (LDS only) -> per-row stats
__global__ __launch_bounds__(256) void k_xa_stats(
    const float* __restrict__ x, const float* __restrict__ ea,
    const float* __restrict__ Wm, const float* __restrict__ cm,
    const float* __restrict__ gwN, const float* __restrict__ gwE,
    float* __restrict__ stats) {
  __shared__ float lx[64][IN_CH];      // 32 KB input tile
  __shared__ float ox[64][HDIM + 1];   // 16.6 KB feature tile (padded)
  __shared__ float lgw[2][64 * DSTALK];
  const int row0 = blockIdx.x * 64;
  const int tid = threadIdx.x;
  for (int i = tid; i < 2 * 64 * DSTALK; i += 256) {
    int which = i / 384, k = i - which * 384;
    lgw[which][k] = which ? gwE[k] : gwN[k];
  }
  for (int i = tid; i < 64 * IN_CH; i += 256) {
    int r = i >> 7, k = i & 127;
    int row = row0 + r;
    float v = 0.f;
    if (row < N_NODES) v = x[row * IN_CH + k];
    else if (row < N_NODES + N_EDGES) v = ea[(row - N_NODES) * IN_CH + k];
    lx[r][k] = v;
  }
  __syncthreads();
  const int col = tid & 63, rg = tid >> 6;  // 4 groups x 16 rows
  float acc[16];
#pragma unroll
  for (int i = 0; i < 16; i++) acc[i] = 0.f;
  for (int k = 0; k < IN_CH; k++) {
    float w = Wm[k * HDIM + col];
#pragma unroll
    for (int i = 0; i < 16; i++) acc[i] += lx[rg * 16 + i][k] * w;
  }
  const float c = cm[col];
#pragma unroll
  for (int i = 0; i < 16; i++) ox[rg * 16 + i][col] = acc[i] + c;
  __syncthreads();
  // 512 reduction tasks: (row, stat). stat: 0=s1, 1=s2, 2..7=p[r]
  for (int t = tid; t < 512; t += 256) {
    int row = t >> 3, st = t & 7;
    int grow = row0 + row;
    if (grow >= N_NODES + N_EDGES) continue;
    const float* __restrict__ gw = (grow >= N_NODES) ? lgw[1] : lgw[0];
    float s = 0.f;
    if (st == 0) {
#pragma unroll 8
      for (int h = 0; h < HDIM; h++) s += ox[row][h];
    } else if (st == 1) {
#pragma unroll 8
      for (int h = 0; h < HDIM; h++) { float v = ox[row][h]; s += v * v; }
    } else {
      int r = st - 2;
#pragma unroll 8
      for (int h = 0; h < HDIM; h++) s += ox[row][h] * gw[h * DSTALK + r];
    }
    stats[(size_t)grow * 8 + st] = s;
  }
}

// ---------------------------------------------------------------------------
// Register-tiled fp32 GEMM: xl0[row][col] = x[row][:] . W0effT[col][:] + c0
// 128x128 tile per block, 8x8 per thread, BK=32, DIRECT staging.
// STABLE OPTIMUM of this structure (95.6us, VGPR 80, zero spill). Ledger:
// - register prefetch (r1-r2): spills ~40MB scratch regardless of VGPR cap
// - full kq unroll (r5): acc spills inside inner loop, 4.4GB HBM traffic
// - A direct from global, B-only LDS (r7): VMEM latency exposed, 161us
// -> A and B both staged to LDS, kq at unroll 1. DO NOT PERTURB.
__global__ __launch_bounds__(256, 2) void k_xl0(
    const float* __restrict__ x, const float* __restrict__ W0effT,
    const float* __restrict__ c0, float* __restrict__ xl0) {
  __shared__ float4 aS[8][129];   // [kq][row], pad residue 4 -> 0-conflict (measured)
  __shared__ float4 bS[8][129];   // [kq][col]
  const int tid = threadIdx.x;
  const int row0 = blockIdx.x * 128;
  const int col0 = blockIdx.y * 128;
  const int tc = tid & 15, tr = tid >> 4;   // 16x16 thread grid
  float acc[8][8];
#pragma unroll
  for (int i = 0; i < 8; i++)
#pragma unroll
    for (int j = 0; j < 8; j++) acc[i][j] = 0.f;

#pragma unroll 1
  for (int kc = 0; kc < 4; kc++) {
    if (kc) __syncthreads();
    // stage A: 1024 float4 (4/thread), direct to LDS
#pragma unroll
    for (int i = 0; i < 4; i++) {
      int fidx = tid + (i << 8);         // 0..1023
      int kq = fidx & 7, row = fidx >> 3;
      int gk = kc * 32 + kq * 4;
      int grow = row0 + row;
      aS[kq][row] = (grow < N_NODES)
                        ? *(const float4*)(x + (size_t)grow * IN_CH + gk)
                        : make_float4(0.f, 0.f, 0.f, 0.f);
    }
    // stage B: 1024 float4 (4/thread)
#pragma unroll
    for (int i = 0; i < 4; i++) {
      int fidx = tid + (i << 8);         // 0..1023
      int kq = fidx & 7, col = fidx >> 3;
      int gk = kc * 32 + kq * 4;
      bS[kq][col] =
          *(const float4*)(W0effT + (size_t)(col0 + col) * IN_CH + gk);
    }
    __syncthreads();
#pragma unroll 1
    for (int kq = 0; kq < 8; kq++) {
      float4 b[8];
#pragma unroll
      for (int j = 0; j < 8; j++) b[j] = bS[kq][tc + (j << 4)];
#pragma unroll
      for (int i = 0; i < 8; i++) {
        float4 a = aS[kq][tr + (i << 4)];
#pragma unroll
        for (int j = 0; j < 8; j++)
          acc[i][j] += a.x * b[j].x + a.y * b[j].y + a.z * b[j].z + a.w * b[j].w;
      }
    }
  }

  float cc[8];
#pragma unroll
  for (int j = 0; j < 8; j++) cc[j] = c0[col0 + tc + (j << 4)];
#pragma unroll
  for (int i = 0; i < 8; i++) {
    int row = row0 + tr + (i << 4);
    if (row >= N_NODES) continue;
    float* __restrict__ orow = xl0 + (size_t)row * HD + col0;
#pragma unroll
    for (int j = 0; j < 8; j++) {
      orow[tc + (j << 4)] = acc[i][j] + cc[j];
    }
  }
}

// ---------------------------------------------------------------------------
// Register-tiled fp32 GEMM: xl = xin @ W1 (K=64, N=64). In-place safe (all
// of a block's reads complete before its epilogue writes; rows are disjoint
// across blocks). 128-row x 64-col tile, 8x4 per thread, BK=32. Round-4
// proven form (see k_xl0 ledger -- same rules apply).
__global__ __launch_bounds__(256) void k_xw(
    const float* __restrict__ xin, const float* __restrict__ W1T,
    float* __restrict__ xl) {
  __shared__ float4 aS[8][129];   // [kq][row] rows=128
  __shared__ float4 bS[8][65];    // [kq][col] cols=64
  const int tid = threadIdx.x;
  const int row0 = blockIdx.x * 128;
  const int tc = tid & 15, tr = tid >> 4;
  float acc[8][4];
#pragma unroll
  for (int i = 0; i < 8; i++)
#pragma unroll
    for (int j = 0; j < 4; j++) acc[i][j] = 0.f;

#pragma unroll 1
  for (int kc = 0; kc < 2; kc++) {
    if (kc) __syncthreads();
    // stage A: 1024 float4 (4/thread)
#pragma unroll
    for (int i = 0; i < 4; i++) {
      int fidx = tid + (i << 8);         // 0..1023
      int kq = fidx & 7, row = fidx >> 3;
      int gk = kc * 32 + kq * 4;
      int grow = row0 + row;
      aS[kq][row] = (grow < NROWS)
                        ? *(const float4*)(xin + (size_t)grow * HDIM + gk)
                        : make_float4(0.f, 0.f, 0.f, 0.f);
    }
    // stage B: 512 float4 (2/thread)
#pragma unroll
    for (int i = 0; i < 2; i++) {
      int fidx = tid + (i << 8);         // 0..511
      int kq = fidx & 7, col = fidx >> 3;
      int gk = kc * 32 + kq * 4;
      bS[kq][col] = *(const float4*)(W1T + col * HDIM + gk);
    }
    __syncthreads();
#pragma unroll 1
    for (int kq = 0; kq < 8; kq++) {
      float4 b[4];
#pragma unroll
      for (int j = 0; j < 4; j++) b[j] = bS[kq][tc + (j << 4)];
#pragma unroll
      for (int i = 0; i < 8; i++) {
        float4 a = aS[kq][tr + (i << 4)];
#pragma unroll
        for (int j = 0; j < 4; j++)
          acc[i][j] += a.x * b[j].x + a.y * b[j].y + a.z * b[j].z + a.w * b[j].w;
      }
    }
  }
#pragma unroll
  for (int i = 0; i < 8; i++) {
    int row = row0 + tr + (i << 4);
    if (row >= NROWS) continue;
#pragma unroll
    for (int j = 0; j < 4; j++) {
      int col = tc + (j << 4);
      xl[(size_t)row * HDIM + col] = acc[i][j];
    }
  }
}

// ---------------------------------------------------------------------------
// conv0 FACTORIZED edge aggregation (round 9): since xl0 = x @ W0effT,
//   msum[e][r*64+h] = Binv[e] * sum_j alpha[j][r] * xl0[n_j][r*64+h]
//                   = sum_k ( Binv[e] * sum_j alpha[j][r] * x[n_j][k] ) * W0effT[r*64+h][k]
// -> gather x-rows (512B/incidence) instead of xl0-rows (1536B/incidence): 3x
//    less gather volume, and x (25.6MB) is L2-resident vs xl0 (76.8MB, L3).
// ax layout: [E][DSTALK][IN_CH]. Binv folded in here (linear).
__global__ __launch_bounds__(256) void k_gather_ex(
    const int* __restrict__ rowE, const int* __restrict__ jlE,
    const int* __restrict__ nlE, const float* __restrict__ alpha,
    const float* __restrict__ x, const float* __restrict__ Binv,
    float* __restrict__ ax) {
  int e = (blockIdx.x * blockDim.x + threadIdx.x) >> 6;
  int lane = threadIdx.x & 63;
  if (e >= N_EDGES) return;
  float acc0[DSTALK], acc1[DSTALK];
#pragma unroll
  for (int r = 0; r < DSTALK; r++) { acc0[r] = 0.f; acc1[r] = 0.f; }
  const int lo = rowE[e], hi = rowE[e + 1];
  int p = lo;
  for (; p + 1 < hi; p += 2) {
    const int j0 = jlE[p],     n0 = nlE[p];
    const int j1 = jlE[p + 1], n1 = nlE[p + 1];
    const float* __restrict__ xr0 = x + (size_t)n0 * IN_CH;
    const float* __restrict__ xr1 = x + (size_t)n1 * IN_CH;
    const float* __restrict__ ar0 = alpha + (size_t)j0 * DSTALK;
    const float* __restrict__ ar1 = alpha + (size_t)j1 * DSTALK;
    float x0a = xr0[lane], x0b = xr0[64 + lane];
    float x1a = xr1[lane], x1b = xr1[64 + lane];
    float a0[DSTALK], a1[DSTALK];
#pragma unroll
    for (int r = 0; r < DSTALK; r++) { a0[r] = ar0[r]; a1[r] = ar1[r]; }
#pragma unroll
    for (int r = 0; r < DSTALK; r++) {
      acc0[r] += a0[r] * x0a + a1[r] * x1a;
      acc1[r] += a0[r] * x0b + a1[r] * x1b;
    }
  }
  if (p < hi) {
    const int j0 = jlE[p], n0 = nlE[p];
    const float* __restrict__ xr0 = x + (size_t)n0 * IN_CH;
    const float* __restrict__ ar0 = alpha + (size_t)j0 * DSTALK;
    float x0a = xr0[lane], x0b = xr0[64 + lane];
#pragma unroll
    for (int r = 0; r < DSTALK; r++) {
      acc0[r] += ar0[r] * x0a;
      acc1[r] += ar0[r] * x0b;
    }
  }
  const float bv = Binv[e];
  float* __restrict__ axe = ax + (size_t)e * (DSTALK * IN_CH);
#pragma unroll
  for (int r = 0; r < DSTALK; r++) {
    axe[r * IN_CH + lane]      = acc0[r] * bv;
    axe[r * IN_CH + 64 + lane] = acc1[r] * bv;
  }
}

// msum[e][r*64+c] = sum_k ax[e][r][k] * W0effT[r*64+c][k]  (Binv already in ax)
// grid (ceil(E/128), DSTALK); 128-edge x 64-col tile, K=128 in 4 chunks of 32.
// Same proven staging/unroll discipline as k_xw.
__global__ __launch_bounds__(256) void k_edge_gemm(
    const float* __restrict__ ax, const float* __restrict__ W0effT,
    float* __restrict__ msum) {
  __shared__ float4 aS[8][129];   // [kq][edge-row]
  __shared__ float4 bS[8][65];    // [kq][col]
  const int tid = threadIdx.x;
  const int e0 = blockIdx.x * 128;
  const int r  = blockIdx.y;
  const int tc = tid & 15, tr = tid >> 4;
  float acc[8][4];
#pragma unroll
  for (int i = 0; i < 8; i++)
#pragma unroll
    for (int j = 0; j < 4; j++) acc[i][j] = 0.f;

#pragma unroll 1
  for (int kc = 0; kc < 4; kc++) {
    if (kc) __syncthreads();
    // stage A: 1024 float4 (4/thread)
#pragma unroll
    for (int i = 0; i < 4; i++) {
      int fidx = tid + (i << 8);         // 0..1023
      int kq = fidx & 7, row = fidx >> 3;
      int gk = kc * 32 + kq * 4;
      int ge = e0 + row;
      aS[kq][row] = (ge < N_EDGES)
          ? *(const float4*)(ax + ((size_t)ge * DSTALK + r) * IN_CH + gk)
          : make_float4(0.f, 0.f, 0.f, 0.f);
    }
    // stage B: 512 float4 (2/thread)
#pragma unroll
    for (int i = 0; i < 2; i++) {
      int fidx = tid + (i << 8);         // 0..511
      int kq = fidx & 7, col = fidx >> 3;
      int gk = kc * 32 + kq * 4;
      bS[kq][col] =
          *(const float4*)(W0effT + (size_t)(r * 64 + col) * IN_CH + gk);
    }
    __syncthreads();
#pragma unroll 1
    for (int kq = 0; kq < 8; kq++) {
      float4 b[4];
#pragma unroll
      for (int j = 0; j < 4; j++) b[j] = bS[kq][tc + (j << 4)];
#pragma unroll
      for (int i = 0; i < 8; i++) {
        float4 a = aS[kq][tr + (i << 4)];
#pragma unroll
        for (int j = 0; j < 4; j++)
          acc[i][j] += a.x * b[j].x + a.y * b[j].y + a.z * b[j].z + a.w * b[j].w;
      }
    }
  }
#pragma unroll
  for (int i = 0; i < 8; i++) {
    int ge = e0 + tr + (i << 4);
    if (ge >= N_EDGES) continue;
    float* __restrict__ mrow = msum + (size_t)ge * HD + r * 64;
#pragma unroll
    for (int j = 0; j < 4; j++) {
      mrow[tc + (j << 4)] = acc[i][j];
    }
  }
}

// ---------------------------------------------------------------------------
// closed-form sheaf coefficients: one THREAD per incidence
__global__ __launch_bounds__(256) void k_sheaf2(
    const int* __restrict__ nidx, const int* __restrict__ eidx,
    const float* __restrict__ stats,
    const float* __restrict__ G, const float* __restrict__ K,
    float* __restrict__ alpha) {
  int j = blockIdx.x * blockDim.x + threadIdx.x;
  if (j >= NNZV) return;
  int n = nidx[j], e = eidx[j];
  const float4* __restrict__ sn = (const float4*)(stats + (size_t)n * 8);
  const float4* __restrict__ se = (const float4*)(stats + ((size_t)(N_NODES + e)) * 8);
  float4 a0 = sn[0], a1 = sn[1];
  float4 b0 = se[0], b1 = se[1];
  float mu = (a0.x + b0.x) * (1.f / 128.f);
  float var = (a0.y + b0.y) * (1.f / 128.f) - mu * mu;
  float rs = rsqrtf(var + 1e-5f);
  float p[DSTALK] = {a0.z + b0.z, a0.w + b0.w, a1.x + b1.x,
                     a1.y + b1.y, a1.z + b1.z, a1.w + b1.w};
#pragma unroll
  for (int r = 0; r < DSTALK; r++) {
    float z = rs * (p[r] - mu * G[r]) + K[r];
    alpha[(size_t)j * DSTALK + r] = 1.f / (1.f + expf(-z));
  }
}

// ---------------------------------------------------------------------------
// degree counts
__global__ void k_count(const int* __restrict__ nidx, const int* __restrict__ eidx,
                        int* __restrict__ cntN, int* __restrict__ cntE) {
  int j = blockIdx.x * blockDim.x + threadIdx.x;
  if (j < NNZV) {
    atomicAdd(&cntN[nidx[j]], 1);
    atomicAdd(&cntE[eidx[j]], 1);
  }
}

// ---------------------------------------------------------------------------
// Multi-block exclusive scan, 512 elements/block.
__global__ __launch_bounds__(256) void k_scan_a(
    const int* __restrict__ cnt, int n, int* __restrict__ row,
    int* __restrict__ bsum) {
  const int b = blockIdx.x, t = threadIdx.x;
  const int i0 = b * 512 + 2 * t, i1 = i0 + 1;
  int c0 = (i0 < n) ? cnt[i0] : 0;
  int c1 = (i1 < n) ? cnt[i1] : 0;
  int ts = c0 + c1;
  const int lane = t & 63, wv = t >> 6;
  int s = ts;
#pragma unroll
  for (int o = 1; o < 64; o <<= 1) {
    int v = __shfl_up(s, o);
    if (lane >= o) s += v;
  }
  __shared__ int wsum[4];
  if (lane == 63) wsum[wv] = s;
  __syncthreads();
  int wbase = 0;
#pragma unroll
  for (int wprev = 0; wprev < 3; wprev++)
    if (wprev < wv) wbase += wsum[wprev];
  const int incl = wbase + s;
  const int excl = incl - ts;
  if (i0 < n) row[i0] = excl;
  if (i1 < n) row[i1] = excl + c0;
  if (t == 255) bsum[b] = incl;
}

__global__ __launch_bounds__(128) void k_scan_b(
    const int* __restrict__ bsum, int nb, int* __restrict__ bbase) {
  const int t = threadIdx.x;
  int v = (t < nb) ? bsum[t] : 0;
  const int lane = t & 63, wv = t >> 6;
  int s = v;
#pragma unroll
  for (int o = 1; o < 64; o <<= 1) {
    int u = __shfl_up(s, o);
    if (lane >= o) s += u;
  }
  __shared__ int wsum[2];
  if (lane == 63) wsum[wv] = s;
  __syncthreads();
  const int incl = ((wv == 1) ? wsum[0] : 0) + s;
  if (t < nb) bbase[t] = incl - v;
  if (t == 127) bbase[nb] = incl;
}

__global__ __launch_bounds__(256) void k_scan_c(
    const int* __restrict__ cnt, const int* __restrict__ bbase, int n, int nb,
    int* __restrict__ row, int* __restrict__ fill, float* __restrict__ inv) {
  int i = blockIdx.x * blockDim.x + threadIdx.x;
  if (i < n) {
    int v = row[i] + bbase[i >> 9];
    row[i] = v;
    fill[i] = v;
    int c = cnt[i];
    inv[i] = c > 0 ? 1.f / (float)c : 0.f;
  }
  if (i == 0) row[n] = bbase[nb];
}

// fill CSR incidence lists + direct neighbor lists (order arbitrary)
__global__ void k_fill(const int* __restrict__ nidx, const int* __restrict__ eidx,
                       int* __restrict__ fillN, int* __restrict__ fillE,
                       int* __restrict__ jlN, int* __restrict__ jlE,
                       int* __restrict__ elN, int* __restrict__ nlE) {
  int j = blockIdx.x * blockDim.x + threadIdx.x;
  if (j < NNZV) {
    int n = nidx[j], e = eidx[j];
    int p = atomicAdd(&fillN[n], 1);
    jlN[p] = j; elN[p] = e;
    int q = atomicAdd(&fillE[e], 1);
    jlE[q] = j; nlE[q] = n;
  }
}

// ---------------------------------------------------------------------------
// gather to edges (conv1 only now): one wave per edge. x4-unrolled grouped
// loads (round-8 verified, neutral vs x2 but harmless).
__global__ __launch_bounds__(256) void k_gather_e(
    const int* __restrict__ rowE, const int* __restrict__ jlE,
    const int* __restrict__ nlE, const float* __restrict__ alpha,
    const float* __restrict__ xl, const float* __restrict__ Binv,
    float* __restrict__ msum) {
  int e = (blockIdx.x * blockDim.x + threadIdx.x) >> 6;
  int lane = threadIdx.x & 63;
  if (e >= N_EDGES) return;
  float acc[DSTALK];
#pragma unroll
  for (int r = 0; r < DSTALK; r++) acc[r] = 0.f;
  const int lo = rowE[e], hi = rowE[e + 1];
  int p = lo;
  for (; p + 3 < hi; p += 4) {
    int jj[4], nn[4];
#pragma unroll
    for (int u = 0; u < 4; u++) { jj[u] = jlE[p + u]; nn[u] = nlE[p + u]; }
    float v[4][DSTALK], a[4][DSTALK];
#pragma unroll
    for (int u = 0; u < 4; u++) {
      const float* __restrict__ xr = xl + (size_t)nn[u] * HD + lane;
      const float* __restrict__ ar = alpha + (size_t)jj[u] * DSTALK;
#pragma unroll
      for (int r = 0; r < DSTALK; r++) { v[u][r] = xr[r * HDIM]; a[u][r] = ar[r]; }
    }
#pragma unroll
    for (int r = 0; r < DSTALK; r++)
      acc[r] += a[0][r] * v[0][r] + a[1][r] * v[1][r] +
                a[2][r] * v[2][r] + a[3][r] * v[3][r];
  }
  for (; p < hi; p++) {
    const int j0 = jlE[p], n0 = nlE[p];
    const float* __restrict__ xr0 = xl + (size_t)n0 * HD + lane;
    const float* __restrict__ ar0 = alpha + (size_t)j0 * DSTALK;
#pragma unroll
    for (int r = 0; r < DSTALK; r++) acc[r] += ar0[r] * xr0[r * HDIM];
  }
  const float bv = Binv[e];
  float* __restrict__ mr = msum + (size_t)e * HD + lane;
#pragma unroll
  for (int r = 0; r < DSTALK; r++) mr[r * HDIM] = acc[r] * bv;
}

// gather back to nodes + bias + ELU epilogue: one wave per node. x4 unroll
// with grouped loads (round-8 verified).
__global__ __launch_bounds__(256) void k_gather_n(
    const int* __restrict__ rowN, const int* __restrict__ jlN,
    const int* __restrict__ elN, const float* __restrict__ alpha,
    const float* __restrict__ msum, const float* __restrict__ Dinv,
    const float* __restrict__ xl, const float* __restrict__ bias,
    float* __restrict__ outp) {
  int n = (blockIdx.x * blockDim.x + threadIdx.x) >> 6;
  int lane = threadIdx.x & 63;
  if (n >= N_NODES) return;
  float acc[DSTALK];
#pragma unroll
  for (int r = 0; r < DSTALK; r++) acc[r] = 0.f;
  const int lo = rowN[n], hi = rowN[n + 1];
  int p = lo;
  for (; p + 3 < hi; p += 4) {
    int jj[4], ee[4];
#pragma unroll
    for (int u = 0; u < 4; u++) { jj[u] = jlN[p + u]; ee[u] = elN[p + u]; }
    float v[4][DSTALK], a[4][DSTALK];
#pragma unroll
    for (int u = 0; u < 4; u++) {
      const float* __restrict__ mr = msum + (size_t)ee[u] * HD + lane;
      const float* __restrict__ ar = alpha + (size_t)jj[u] * DSTALK;
#pragma unroll
      for (int r = 0; r < DSTALK; r++) { v[u][r] = mr[r * HDIM]; a[u][r] = ar[r]; }
    }
#pragma unroll
    for (int r = 0; r < DSTALK; r++)
      acc[r] += a[0][r] * v[0][r] + a[1][r] * v[1][r] +
                a[2][r] * v[2][r] + a[3][r] * v[3][r];
  }
  for (; p < hi; p++) {
    const int j0 = jlN[p], e0 = elN[p];
    const float* __restrict__ mr0 = msum + (size_t)e0 * HD + lane;
    const float* __restrict__ ar0 = alpha + (size_t)j0 * DSTALK;
#pragma unroll
    for (int r = 0; r < DSTALK; r++) acc[r] += ar0[r] * mr0[r * HDIM];
  }
  const float dv = Dinv[n];
  const float bb = bias[lane];
  const float* __restrict__ xr = xl + (size_t)n * HD + lane;
  float* __restrict__ orow = outp + (size_t)n * HD + lane;
#pragma unroll
  for (int r = 0; r < DSTALK; r++) {
    float v = xr[r * HDIM] + bb - dv * acc[r];
    orow[r * HDIM] = v > 0.f ? v : expm1f(v);
  }
}

// ---------------------------------------------------------------------------
extern "C" void kernel_launch(void* const* d_in, const int* in_sizes, int n_in,
                              void* d_out, int out_size, void* d_ws, size_t ws_size,
                              hipStream_t stream) {
  const float* x    = (const float*)d_in[0];
  const float* hea  = (const float*)d_in[1];
  const int*  nidx  = (const int*)d_in[2];
  const int*  eidx  = (const int*)d_in[3];
  // d_in[4], d_in[5] = node_types / hyperedge_types: unused by reference
  const float* W_lin = (const float*)d_in[6];
  const float* b_lin = (const float*)d_in[7];
  const float* ln_g  = (const float*)d_in[8];
  const float* ln_b  = (const float*)d_in[9];
  const float* W_sh  = (const float*)d_in[10];
  const float* b_sh  = (const float*)d_in[11];
  const float* W_c0  = (const float*)d_in[12];
  const float* b_c0  = (const float*)d_in[13];
  const float* W_c1  = (const float*)d_in[14];
  const float* b_c1  = (const float*)d_in[15];
  float* out = (float*)d_out;

  // workspace layout (f32), 256B aligned. Total ~105 MB.
  char* ws = (char*)d_ws;
  size_t off = 0;
  auto alloc = [&](size_t bytes) {
    size_t o = off;
    off = (off + bytes + 255) & ~(size_t)255;
    return o;
  };
  size_t o_xl0   = alloc((size_t)NROWS * HDIM * 4);               // 76.8 MB
  size_t o_msum  = alloc((size_t)EROWS * HDIM * 4);               // 15.36 MB
  size_t o_alpha = alloc((size_t)NNZV * DSTALK * 4);              // 6 MB
  size_t o_stats = alloc((size_t)(N_NODES + N_EDGES) * 8 * 4);    // 1.92 MB
  size_t o_jlN   = alloc((size_t)NNZV * 4);                       // 1 MB
  size_t o_jlE   = alloc((size_t)NNZV * 4);                       // 1 MB
  size_t o_elN   = alloc((size_t)NNZV * 4);                       // 1 MB
  size_t o_nlE   = alloc((size_t)NNZV * 4);                       // 1 MB
  size_t o_cntN  = alloc((size_t)N_NODES * 4);
  size_t o_cntE  = alloc((size_t)N_EDGES * 4);
  size_t o_rowN  = alloc((size_t)(N_NODES + 1) * 4);
  size_t o_rowE  = alloc((size_t)(N_EDGES + 1) * 4);
  size_t o_filN  = alloc((size_t)N_NODES * 4);
  size_t o_filE  = alloc((size_t)N_EDGES * 4);
  size_t o_Dinv  = alloc((size_t)N_NODES * 4);
  size_t o_Binv  = alloc((size_t)N_EDGES * 4);
  size_t o_bsN   = alloc((size_t)256 * 4);
  size_t o_bbN   = alloc((size_t)256 * 4);
  size_t o_bsE   = alloc((size_t)256 * 4);
  size_t o_bbE   = alloc((size_t)256 * 4);
  size_t o_WeffT = alloc((size_t)IN_CH * HD * 4);                 // 196 KB
  size_t o_Wm    = alloc((size_t)IN_CH * HDIM * 4);               // 32 KB
  size_t o_cm    = alloc((size_t)HDIM * 4);
  size_t o_c0    = alloc((size_t)HD * 4);
  size_t o_gwN   = alloc((size_t)64 * DSTALK * 4);
  size_t o_gwE   = alloc((size_t)64 * DSTALK * 4);
  size_t o_G     = alloc((size_t)DSTALK * 4);
  size_t o_K     = alloc((size_t)DSTALK * 4);
  size_t o_W1T   = alloc((size_t)HDIM * HDIM * 4);                // 16 KB

  float* xl0    = (float*)(ws + o_xl0);
  float* msum   = (float*)(ws + o_msum);
  float* alpha  = (float*)(ws + o_alpha);
  float* stats  = (float*)(ws + o_stats);
  int*   jlN    = (int*)(ws + o_jlN);
  int*   jlE    = (int*)(ws + o_jlE);
  int*   elN    = (int*)(ws + o_elN);
  int*   nlE    = (int*)(ws + o_nlE);
  int*   cntN   = (int*)(ws + o_cntN);
  int*   cntE   = (int*)(ws + o_cntE);
  int*   rowN   = (int*)(ws + o_rowN);
  int*   rowE   = (int*)(ws + o_rowE);
  int*   filN   = (int*)(ws + o_filN);
  int*   filE   = (int*)(ws + o_filE);
  float* Dinv   = (float*)(ws + o_Dinv);
  float* Binv   = (float*)(ws + o_Binv);
  int*   bsN    = (int*)(ws + o_bsN);
  int*   bbN    = (int*)(ws + o_bbN);
  int*   bsE    = (int*)(ws + o_bsE);
  int*   bbE    = (int*)(ws + o_bbE);
  float* W0effT = (float*)(ws + o_WeffT);
  float* Wm     = (float*)(ws + o_Wm);
  float* cm     = (float*)(ws + o_cm);
  float* c0     = (float*)(ws + o_c0);
  float* gwN    = (float*)(ws + o_gwN);
  float* gwE    = (float*)(ws + o_gwE);
  float* G      = (float*)(ws + o_G);
  float* K      = (float*)(ws + o_K);
  float* W1T    = (float*)(ws + o_W1T);

  // ax scratch [E][6][128] = 30.7 MB lives in d_out (76.8 MB): fully consumed
  // by k_edge_gemm before the final k_gather_n overwrites out.
  float* ax = (float*)d_out;

  const int NB_N = (N_NODES + 511) / 512;  // 98
  const int NB_E = (N_EDGES + 511) / 512;  // 20

  // 0. weight prep
  k_wefft<<<(IN_CH * HD + 255) / 256, 256, 0, stream>>>(W_lin, W_c0, W0effT);
  k_wsmall<<<(WS_END + 255) / 256, 256, 0, stream>>>(
      W_lin, b_lin, W_c0, W_c1, ln_g, ln_b, W_sh, b_sh,
      Wm, cm, c0, gwN, gwE, G, K, W1T);

  // 1. CSR build: counts -> parallel scans (+Dinv/Binv) -> fill
  hipMemsetAsync(ws + o_cntN, 0, (size_t)N_NODES * 4, stream);
  hipMemsetAsync(ws + o_cntE, 0, (size_t)N_EDGES * 4, stream);
  k_count<<<(NNZV + 255) / 256, 256, 0, stream>>>(nidx, eidx, cntN, cntE);
  k_scan_a<<<NB_N, 256, 0, stream>>>(cntN, N_NODES, rowN, bsN);
  k_scan_a<<<NB_E, 256, 0, stream>>>(cntE, N_EDGES, rowE, bsE);
  k_scan_b<<<1, 128, 0, stream>>>(bsN, NB_N, bbN);
  k_scan_b<<<1, 128, 0, stream>>>(bsE, NB_E, bbE);
  k_scan_c<<<(N_NODES + 255) / 256, 256, 0, stream>>>(cntN, bbN, N_NODES, NB_N,
                                                      rowN, filN, Dinv);
  k_scan_c<<<(N_EDGES + 255) / 256, 256, 0, stream>>>(cntE, bbE, N_EDGES, NB_E,
                                                      rowE, filE, Binv);
  k_fill<<<(NNZV + 255) / 256, 256, 0, stream>>>(nidx, eidx, filN, filE,
                                                 jlN, jlE, elN, nlE);

  // 2. fused stalk-mean + LN sufficient stats
  k_xa_stats<<<(N_NODES + N_EDGES + 63) / 64, 256, 0, stream>>>(
      x, hea, Wm, cm, gwN, gwE, stats);

  // 3. closed-form sheaf coefficients alpha [NNZ x 6]
  k_sheaf2<<<(NNZV + 255) / 256, 256, 0, stream>>>(nidx, eidx, stats, G, K, alpha);

  // 4. conv0 (factorized): gather x-space edge aggregates -> edge GEMM -> msum;
  //    node GEMM xl0; node gather + bias + ELU.
  k_gather_ex<<<(N_EDGES + 3) / 4, 256, 0, stream>>>(rowE, jlE, nlE, alpha, x,
                                                     Binv, ax);
  {
    dim3 ge((N_EDGES + 127) / 128, DSTALK);  // (79, 6)
    k_edge_gemm<<<ge, 256, 0, stream>>>(ax, W0effT, msum);
  }
  {
    dim3 g((N_NODES + 127) / 128, HD / 128);   // (391, 3)
    k_xl0<<<g, 256, 0, stream>>>(x, W0effT, c0, xl0);
  }
  k_gather_n<<<(N_NODES + 3) / 4, 256, 0, stream>>>(rowN, jlN, elN, alpha, msum, Dinv,
                                                    xl0, b_c0, xl0);  // xl0 now holds h1

  // 5. conv1: xl1 = h1@W1 (in place); gather-diffusion; bias+ELU into d_out
  k_xw<<<(NROWS + 127) / 128, 256, 0, stream>>>(xl0, W1T, xl0);
  k_gather_e<<<(N_EDGES + 3) / 4, 256, 0, stream>>>(rowE, jlE, nlE, alpha, xl0, Binv, msum);
  k_gather_n<<<(N_NODES + 3) / 4, 256, 0, stream>>>(rowN, jlN, elN, alpha, msum, Dinv,
                                                    xl0, b_c1, out);

  (void)in_sizes; (void)n_in; (void)out_size; (void)ws_size;
}

// Round 11
// 626.776 us; speedup vs baseline: 1.2031x; 1.0412x over previous
//
#include <hip/hip_runtime.h>
#include <hip/hip_bf16.h>

// Problem constants (from reference)
#define N_NODES 50000
#define N_EDGES 10000
#define NNZV    250000
#define IN_CH   128
#define HDIM    64
#define DSTALK  6
#define HD      384   // HDIM * DSTALK
#define NROWS   (N_NODES * DSTALK)   // 300000
#define EROWS   (N_EDGES * DSTALK)   // 60000

typedef __attribute__((ext_vector_type(8))) short bf16x8;
typedef __attribute__((ext_vector_type(4))) float f32x4;

// ---------------------------------------------------------------------------
// W-prep 1: W0effT[j][k] = sum_m W_lin[k][r*64+m] * W0[m][h]  (j=r*64+h)
// transposed [384][128] so the GEMM can vector-load along k.
__global__ __launch_bounds__(256) void k_wefft(
    const float* __restrict__ W_lin, const float* __restrict__ W0,
    float* __restrict__ W0effT) {
  int idx = blockIdx.x * blockDim.x + threadIdx.x;
  if (idx >= IN_CH * HD) return;
  int k = idx / HD, j = idx - k * HD;
  int r = j >> 6, h = j & 63;
  float s = 0.f;
#pragma unroll 8
  for (int m = 0; m < HDIM; m++)
    s += W_lin[k * HD + r * HDIM + m] * W0[m * HDIM + h];
  W0effT[(size_t)j * IN_CH + k] = s;
}

// W-prep 2: Wm, cm, c0 + sheaf tables gwN/gwE/G/K + W1T transpose
#define WS_BASE (IN_CH * HDIM + HD + HDIM)   // 8640
#define WS_END  (WS_BASE + 780 + HDIM * HDIM)
__global__ __launch_bounds__(256) void k_wsmall(
    const float* __restrict__ W_lin, const float* __restrict__ b_lin,
    const float* __restrict__ W0, const float* __restrict__ W1,
    const float* __restrict__ g, const float* __restrict__ bln,
    const float* __restrict__ Ws, const float* __restrict__ bs,
    float* __restrict__ Wm, float* __restrict__ cm, float* __restrict__ c0,
    float* __restrict__ gwN, float* __restrict__ gwE,
    float* __restrict__ G, float* __restrict__ K, float* __restrict__ W1T) {
  int idx = blockIdx.x * blockDim.x + threadIdx.x;
  if (idx < IN_CH * HDIM) {            // Wm
    int k = idx >> 6, h = idx & 63;
    float s = 0.f;
#pragma unroll
    for (int r = 0; r < DSTALK; r++) s += W_lin[k * HD + r * HDIM + h];
    Wm[idx] = s * (1.f / 6.f);
  } else if (idx < IN_CH * HDIM + HD) {  // c0
    int j = idx - IN_CH * HDIM;
    int r = j >> 6, h = j & 63;
    float s = 0.f;
#pragma unroll 8
    for (int m = 0; m < HDIM; m++) s += b_lin[r * HDIM + m] * W0[m * HDIM + h];
    c0[j] = s;
  } else if (idx < WS_BASE) {  // cm
    int h = idx - IN_CH * HDIM - HD;
    float s = 0.f;
#pragma unroll
    for (int r = 0; r < DSTALK; r++) s += b_lin[r * HDIM + h];
    cm[h] = s * (1.f / 6.f);
  } else if (idx < WS_BASE + 384) {      // gwN
    int i = idx - WS_BASE;
    int h = i / 6, r = i - h * 6;
    gwN[i] = g[h] * Ws[h * DSTALK + r];
  } else if (idx < WS_BASE + 768) {      // gwE
    int i = idx - WS_BASE - 384;
    int h = i / 6, r = i - h * 6;
    gwE[i] = g[64 + h] * Ws[(64 + h) * DSTALK + r];
  } else if (idx < WS_BASE + 774) {      // G
    int r = idx - WS_BASE - 768;
    float s = 0.f;
    for (int i = 0; i < 2 * HDIM; i++) s += g[i] * Ws[i * DSTALK + r];
    G[r] = s;
  } else if (idx < WS_BASE + 780) {      // K
    int r = idx - WS_BASE - 774;
    float s = 0.f;
    for (int i = 0; i < 2 * HDIM; i++) s += bln[i] * Ws[i * DSTALK + r];
    K[r] = s + bs[r];
  } else if (idx < WS_END) {             // W1T[c][k] = W1[k][c]
    int i = idx - WS_BASE - 780;
    int c = i >> 6, k = i & 63;
    W1T[c * HDIM + k] = W1[k * HDIM + c];
  }
}

// ---------------------------------------------------------------------------
// split fp32 -> bf16 hi + bf16 lo (RN both). Residual after hi+lo ~2^-17 rel.
__global__ __launch_bounds__(256) void k_split(
    const float* __restrict__ src, int n4,
    unsigned short* __restrict__ hi, unsigned short* __restrict__ lo) {
  int i = blockIdx.x * blockDim.x + threadIdx.x;
  if (i >= n4) return;
  float4 v = ((const float4*)src)[i];
  float f[4] = {v.x, v.y, v.z, v.w};
  unsigned short h[4], l[4];
#pragma unroll
  for (int u = 0; u < 4; u++) {
    unsigned int b = __float_as_uint(f[u]);
    unsigned int r = (b + 0x7FFFu + ((b >> 16) & 1u)) >> 16;
    h[u] = (unsigned short)r;
    float d = f[u] - __uint_as_float(r << 16);
    unsigned int b2 = __float_as_uint(d);
    unsigned int r2 = (b2 + 0x7FFFu + ((b2 >> 16) & 1u)) >> 16;
    l[u] = (unsigned short)r2;
  }
  ((ushort4*)hi)[i] = make_ushort4(h[0], h[1], h[2], h[3]);
  ((ushort4*)lo)[i] = make_ushort4(l[0], l[1], l[2], l[3]);
}

// ---------------------------------------------------------------------------
// Fused: row features xa = [x;hea]@Wm + cm (LDS only) -> per-row stats
__global__ __launch_bounds__(256) void k_xa_stats(
    const float* __restrict__ x, const float* __restrict__ ea,
    const float* __restrict__ Wm, const float* __restrict__ cm,
    const float* __restrict__ gwN, const float* __restrict__ gwE,
    float* __restrict__ stats) {
  __shared__ float lx[64][IN_CH];      // 32 KB input tile
  __shared__ float ox[64][HDIM + 1];   // 16.6 KB feature tile (padded)
  __shared__ float lgw[2][64 * DSTALK];
  const int row0 = blockIdx.x * 64;
  const int tid = threadIdx.x;
  for (int i = tid; i < 2 * 64 * DSTALK; i += 256) {
    int which = i / 384, k = i - which * 384;
    lgw[which][k] = which ? gwE[k] : gwN[k];
  }
  for (int i = tid; i < 64 * IN_CH; i += 256) {
    int r = i >> 7, k = i & 127;
    int row = row0 + r;
    float v = 0.f;
    if (row < N_NODES) v = x[row * IN_CH + k];
    else if (row < N_NODES + N_EDGES) v = ea[(row - N_NODES) * IN_CH + k];
    lx[r][k] = v;
  }
  __syncthreads();
  const int col = tid & 63, rg = tid >> 6;  // 4 groups x 16 rows
  float acc[16];
#pragma unroll
  for (int i = 0; i < 16; i++) acc[i] = 0.f;
  for (int k = 0; k < IN_CH; k++) {
    float w = Wm[k * HDIM + col];
#pragma unroll
    for (int i = 0; i < 16; i++) acc[i] += lx[rg * 16 + i][k] * w;
  }
  const float c = cm[col];
#pragma unroll
  for (int i = 0; i < 16; i++) ox[rg * 16 + i][col] = acc[i] + c;
  __syncthreads();
  // 512 reduction tasks: (row, stat). stat: 0=s1, 1=s2, 2..7=p[r]
  for (int t = tid; t < 512; t += 256) {
    int row = t >> 3, st = t & 7;
    int grow = row0 + row;
    if (grow >= N_NODES + N_EDGES) continue;
    const float* __restrict__ gw = (grow >= N_NODES) ? lgw[1] : lgw[0];
    float s = 0.f;
    if (st == 0) {
#pragma unroll 8
      for (int h = 0; h < HDIM; h++) s += ox[row][h];
    } else if (st == 1) {
#pragma unroll 8
      for (int h = 0; h < HDIM; h++) { float v = ox[row][h]; s += v * v; }
    } else {
      int r = st - 2;
#pragma unroll 8
      for (int h = 0; h < HDIM; h++) s += ox[row][h] * gw[h * DSTALK + r];
    }
    stats[(size_t)grow * 8 + st] = s;
  }
}

// ---------------------------------------------------------------------------
// k_xl0 v3: split-bf16 MFMA GEMM.
// xl0 = x @ W0effT + c0 with x = xh+xl, W = wh+wl (bf16 RN pairs);
// C ~= xh*wh + xh*wl + xl*wh (lo*lo dropped, ~2^-17 rel).
// 128x128 tile, 4 waves x (32 rows x 128 cols), K=128 in 4 steps of 32.
// mfma_f32_16x16x32_bf16 layouts: A row=lane&15 k=(lane>>4)*8+j;
// B col=lane&15 same k; D col=lane&15 row=(lane>>4)*4+reg (m89-verified).
__global__ __launch_bounds__(256, 2) void k_xl0(
    const unsigned short* __restrict__ xh, const unsigned short* __restrict__ xl,
    const unsigned short* __restrict__ wh, const unsigned short* __restrict__ wl,
    const float* __restrict__ c0, float* __restrict__ xl0) {
  __shared__ bf16x8 aH[4][132], aL[4][132], bH[4][132], bL[4][132];
  const int tid = threadIdx.x;
  const int row0 = blockIdx.x * 128;
  const int col0 = blockIdx.y * 128;
  const int lane = tid & 63, wv = tid >> 6;
  const int wrow = wv * 32;
  const int kg = lane >> 4, rr = lane & 15;
  f32x4 acc[2][8];
#pragma unroll
  for (int i = 0; i < 2; i++)
#pragma unroll
    for (int j = 0; j < 8; j++) acc[i][j] = (f32x4){0.f, 0.f, 0.f, 0.f};

#pragma unroll 1
  for (int ks = 0; ks < 4; ks++) {
    if (ks) __syncthreads();
    const int kbase = ks * 32;
    // stage: 512 bf16x8 per array x 4 arrays = 8 writes/thread
#pragma unroll
    for (int i = 0; i < 2; i++) {
      int f2 = tid + (i << 8);          // 0..511
      int g = f2 & 3, rc = f2 >> 2;     // kgroup 0..3, row/col 0..127
      bf16x8 zv = {0, 0, 0, 0, 0, 0, 0, 0};
      int grow = row0 + rc;
      const size_t soff = (size_t)grow * IN_CH + kbase + g * 8;
      bool ok = (grow < N_NODES);
      aH[g][rc] = ok ? *(const bf16x8*)(xh + soff) : zv;
      aL[g][rc] = ok ? *(const bf16x8*)(xl + soff) : zv;
      const size_t woff = (size_t)(col0 + rc) * IN_CH + kbase + g * 8;
      bH[g][rc] = *(const bf16x8*)(wh + woff);
      bL[g][rc] = *(const bf16x8*)(wl + woff);
    }
    __syncthreads();
    bf16x8 a0h = aH[kg][wrow + rr];
    bf16x8 a0l = aL[kg][wrow + rr];
    bf16x8 a1h = aH[kg][wrow + 16 + rr];
    bf16x8 a1l = aL[kg][wrow + 16 + rr];
#pragma unroll
    for (int cb = 0; cb < 8; cb++) {
      bf16x8 vbh = bH[kg][cb * 16 + rr];
      bf16x8 vbl = bL[kg][cb * 16 + rr];
      acc[0][cb] = __builtin_amdgcn_mfma_f32_16x16x32_bf16(a0h, vbh, acc[0][cb], 0, 0, 0);
      acc[0][cb] = __builtin_amdgcn_mfma_f32_16x16x32_bf16(a0h, vbl, acc[0][cb], 0, 0, 0);
      acc[0][cb] = __builtin_amdgcn_mfma_f32_16x16x32_bf16(a0l, vbh, acc[0][cb], 0, 0, 0);
      acc[1][cb] = __builtin_amdgcn_mfma_f32_16x16x32_bf16(a1h, vbh, acc[1][cb], 0, 0, 0);
      acc[1][cb] = __builtin_amdgcn_mfma_f32_16x16x32_bf16(a1h, vbl, acc[1][cb], 0, 0, 0);
      acc[1][cb] = __builtin_amdgcn_mfma_f32_16x16x32_bf16(a1l, vbh, acc[1][cb], 0, 0, 0);
    }
  }

  // epilogue: D[row=(lane>>4)*4+r within subtile][col=lane&15]
#pragma unroll
  for (int cb = 0; cb < 8; cb++) {
    float cc = c0[col0 + cb * 16 + rr];
#pragma unroll
    for (int rb = 0; rb < 2; rb++) {
#pragma unroll
      for (int r = 0; r < 4; r++) {
        int row = row0 + wrow + rb * 16 + kg * 4 + r;
        if (row < N_NODES)
          xl0[(size_t)row * HD + col0 + cb * 16 + rr] = acc[rb][cb][r] + cc;
      }
    }
  }
}

// ---------------------------------------------------------------------------
// Register-tiled fp32 GEMM: xl = xin @ W1 (K=64, N=64). In-place safe (all
// of a block's reads complete before its epilogue writes; rows are disjoint
// across blocks). 128-row x 64-col tile, 8x4 per thread, BK=32. Round-4
// proven form (direct staging, kq at unroll 1 -- see session ledger).
__global__ __launch_bounds__(256) void k_xw(
    const float* __restrict__ xin, const float* __restrict__ W1T,
    float* __restrict__ xl) {
  __shared__ float4 aS[8][129];   // [kq][row] rows=128
  __shared__ float4 bS[8][65];    // [kq][col] cols=64
  const int tid = threadIdx.x;
  const int row0 = blockIdx.x * 128;
  const int tc = tid & 15, tr = tid >> 4;
  float acc[8][4];
#pragma unroll
  for (int i = 0; i < 8; i++)
#pragma unroll
    for (int j = 0; j < 4; j++) acc[i][j] = 0.f;

#pragma unroll 1
  for (int kc = 0; kc < 2; kc++) {
    if (kc) __syncthreads();
    // stage A: 1024 float4 (4/thread)
#pragma unroll
    for (int i = 0; i < 4; i++) {
      int fidx = tid + (i << 8);         // 0..1023
      int kq = fidx & 7, row = fidx >> 3;
      int gk = kc * 32 + kq * 4;
      int grow = row0 + row;
      aS[kq][row] = (grow < NROWS)
                        ? *(const float4*)(xin + (size_t)grow * HDIM + gk)
                        : make_float4(0.f, 0.f, 0.f, 0.f);
    }
    // stage B: 512 float4 (2/thread)
#pragma unroll
    for (int i = 0; i < 2; i++) {
      int fidx = tid + (i << 8);         // 0..511
      int kq = fidx & 7, col = fidx >> 3;
      int gk = kc * 32 + kq * 4;
      bS[kq][col] = *(const float4*)(W1T + col * HDIM + gk);
    }
    __syncthreads();
#pragma unroll 1
    for (int kq = 0; kq < 8; kq++) {
      float4 b[4];
#pragma unroll
      for (int j = 0; j < 4; j++) b[j] = bS[kq][tc + (j << 4)];
#pragma unroll
      for (int i = 0; i < 8; i++) {
        float4 a = aS[kq][tr + (i << 4)];
#pragma unroll
        for (int j = 0; j < 4; j++)
          acc[i][j] += a.x * b[j].x + a.y * b[j].y + a.z * b[j].z + a.w * b[j].w;
      }
    }
  }
#pragma unroll
  for (int i = 0; i < 8; i++) {
    int row = row0 + tr + (i << 4);
    if (row >= NROWS) continue;
#pragma unroll
    for (int j = 0; j < 4; j++) {
      int col = tc + (j << 4);
      xl[(size_t)row * HDIM + col] = acc[i][j];
    }
  }
}

// ---------------------------------------------------------------------------
// conv0 FACTORIZED edge aggregation: since xl0 = x @ W0effT,
//   msum[e] = (Binv[e] * sum_j alpha_j x[n_j]) @ W0effT  -- gather in x-space
// (512B/incidence vs 1536B), then a small dense GEMM.
__global__ __launch_bounds__(256) void k_gather_ex(
    const int* __restrict__ rowE, const int* __restrict__ jlE,
    const int* __restrict__ nlE, const float* __restrict__ alpha,
    const float* __restrict__ x, const float* __restrict__ Binv,
    float* __restrict__ ax) {
  int e = (blockIdx.x * blockDim.x + threadIdx.x) >> 6;
  int lane = threadIdx.x & 63;
  if (e >= N_EDGES) return;
  float acc0[DSTALK], acc1[DSTALK];
#pragma unroll
  for (int r = 0; r < DSTALK; r++) { acc0[r] = 0.f; acc1[r] = 0.f; }
  const int lo = rowE[e], hi = rowE[e + 1];
  int p = lo;
  for (; p + 1 < hi; p += 2) {
    const int j0 = jlE[p],     n0 = nlE[p];
    const int j1 = jlE[p + 1], n1 = nlE[p + 1];
    const float* __restrict__ xr0 = x + (size_t)n0 * IN_CH;
    const float* __restrict__ xr1 = x + (size_t)n1 * IN_CH;
    const float* __restrict__ ar0 = alpha + (size_t)j0 * DSTALK;
    const float* __restrict__ ar1 = alpha + (size_t)j1 * DSTALK;
    float x0a = xr0[lane], x0b = xr0[64 + lane];
    float x1a = xr1[lane], x1b = xr1[64 + lane];
    float a0[DSTALK], a1[DSTALK];
#pragma unroll
    for (int r = 0; r < DSTALK; r++) { a0[r] = ar0[r]; a1[r] = ar1[r]; }
#pragma unroll
    for (int r = 0; r < DSTALK; r++) {
      acc0[r] += a0[r] * x0a + a1[r] * x1a;
      acc1[r] += a0[r] * x0b + a1[r] * x1b;
    }
  }
  if (p < hi) {
    const int j0 = jlE[p], n0 = nlE[p];
    const float* __restrict__ xr0 = x + (size_t)n0 * IN_CH;
    const float* __restrict__ ar0 = alpha + (size_t)j0 * DSTALK;
    float x0a = xr0[lane], x0b = xr0[64 + lane];
#pragma unroll
    for (int r = 0; r < DSTALK; r++) {
      acc0[r] += ar0[r] * x0a;
      acc1[r] += ar0[r] * x0b;
    }
  }
  const float bv = Binv[e];
  float* __restrict__ axe = ax + (size_t)e * (DSTALK * IN_CH);
#pragma unroll
  for (int r = 0; r < DSTALK; r++) {
    axe[r * IN_CH + lane]      = acc0[r] * bv;
    axe[r * IN_CH + 64 + lane] = acc1[r] * bv;
  }
}

// msum[e][r*64+c] = sum_k ax[e][r][k] * W0effT[r*64+c][k]  (Binv already in ax)
__global__ __launch_bounds__(256) void k_edge_gemm(
    const float* __restrict__ ax, const float* __restrict__ W0effT,
    float* __restrict__ msum) {
  __shared__ float4 aS[8][129];   // [kq][edge-row]
  __shared__ float4 bS[8][65];    // [kq][col]
  const int tid = threadIdx.x;
  const int e0 = blockIdx.x * 128;
  const int r  = blockIdx.y;
  const int tc = tid & 15, tr = tid >> 4;
  float acc[8][4];
#pragma unroll
  for (int i = 0; i < 8; i++)
#pragma unroll
    for (int j = 0; j < 4; j++) acc[i][j] = 0.f;

#pragma unroll 1
  for (int kc = 0; kc < 4; kc++) {
    if (kc) __syncthreads();
#pragma unroll
    for (int i = 0; i < 4; i++) {
      int fidx = tid + (i << 8);         // 0..1023
      int kq = fidx & 7, row = fidx >> 3;
      int gk = kc * 32 + kq * 4;
      int ge = e0 + row;
      aS[kq][row] = (ge < N_EDGES)
          ? *(const float4*)(ax + ((size_t)ge * DSTALK + r) * IN_CH + gk)
          : make_float4(0.f, 0.f, 0.f, 0.f);
    }
#pragma unroll
    for (int i = 0; i < 2; i++) {
      int fidx = tid + (i << 8);         // 0..511
      int kq = fidx & 7, col = fidx >> 3;
      int gk = kc * 32 + kq * 4;
      bS[kq][col] =
          *(const float4*)(W0effT + (size_t)(r * 64 + col) * IN_CH + gk);
    }
    __syncthreads();
#pragma unroll 1
    for (int kq = 0; kq < 8; kq++) {
      float4 b[4];
#pragma unroll
      for (int j = 0; j < 4; j++) b[j] = bS[kq][tc + (j << 4)];
#pragma unroll
      for (int i = 0; i < 8; i++) {
        float4 a = aS[kq][tr + (i << 4)];
#pragma unroll
        for (int j = 0; j < 4; j++)
          acc[i][j] += a.x * b[j].x + a.y * b[j].y + a.z * b[j].z + a.w * b[j].w;
      }
    }
  }
#pragma unroll
  for (int i = 0; i < 8; i++) {
    int ge = e0 + tr + (i << 4);
    if (ge >= N_EDGES) continue;
    float* __restrict__ mrow = msum + (size_t)ge * HD + r * 64;
#pragma unroll
    for (int j = 0; j < 4; j++) {
      mrow[tc + (j << 4)] = acc[i][j];
    }
  }
}

// ---------------------------------------------------------------------------
// closed-form sheaf coefficients: one THREAD per incidence
__global__ __launch_bounds__(256) void k_sheaf2(
    const int* __restrict__ nidx, const int* __restrict__ eidx,
    const float* __restrict__ stats,
    const float* __restrict__ G, const float* __restrict__ K,
    float* __restrict__ alpha) {
  int j = blockIdx.x * blockDim.x + threadIdx.x;
  if (j >= NNZV) return;
  int n = nidx[j], e = eidx[j];
  const float4* __restrict__ sn = (const float4*)(stats + (size_t)n * 8);
  const float4* __restrict__ se = (const float4*)(stats + ((size_t)(N_NODES + e)) * 8);
  float4 a0 = sn[0], a1 = sn[1];
  float4 b0 = se[0], b1 = se[1];
  float mu = (a0.x + b0.x) * (1.f / 128.f);
  float var = (a0.y + b0.y) * (1.f / 128.f) - mu * mu;
  float rs = rsqrtf(var + 1e-5f);
  float p[DSTALK] = {a0.z + b0.z, a0.w + b0.w, a1.x + b1.x,
                     a1.y + b1.y, a1.z + b1.z, a1.w + b1.w};
#pragma unroll
  for (int r = 0; r < DSTALK; r++) {
    float z = rs * (p[r] - mu * G[r]) + K[r];
    alpha[(size_t)j * DSTALK + r] = 1.f / (1.f + expf(-z));
  }
}

// ---------------------------------------------------------------------------
// degree counts
__global__ void k_count(const int* __restrict__ nidx, const int* __restrict__ eidx,
                        int* __restrict__ cntN, int* __restrict__ cntE) {
  int j = blockIdx.x * blockDim.x + threadIdx.x;
  if (j < NNZV) {
    atomicAdd(&cntN[nidx[j]], 1);
    atomicAdd(&cntE[eidx[j]], 1);
  }
}

// ---------------------------------------------------------------------------
// Multi-block exclusive scan, 512 elements/block.
__global__ __launch_bounds__(256) void k_scan_a(
    const int* __restrict__ cnt, int n, int* __restrict__ row,
    int* __restrict__ bsum) {
  const int b = blockIdx.x, t = threadIdx.x;
  const int i0 = b * 512 + 2 * t, i1 = i0 + 1;
  int c0 = (i0 < n) ? cnt[i0] : 0;
  int c1 = (i1 < n) ? cnt[i1] : 0;
  int ts = c0 + c1;
  const int lane = t & 63, wv = t >> 6;
  int s = ts;
#pragma unroll
  for (int o = 1; o < 64; o <<= 1) {
    int v = __shfl_up(s, o);
    if (lane >= o) s += v;
  }
  __shared__ int wsum[4];
  if (lane == 63) wsum[wv] = s;
  __syncthreads();
  int wbase = 0;
#pragma unroll
  for (int wprev = 0; wprev < 3; wprev++)
    if (wprev < wv) wbase += wsum[wprev];
  const int incl = wbase + s;
  const int excl = incl - ts;
  if (i0 < n) row[i0] = excl;
  if (i1 < n) row[i1] = excl + c0;
  if (t == 255) bsum[b] = incl;
}

__global__ __launch_bounds__(128) void k_scan_b(
    const int* __restrict__ bsum, int nb, int* __restrict__ bbase) {
  const int t = threadIdx.x;
  int v = (t < nb) ? bsum[t] : 0;
  const int lane = t & 63, wv = t >> 6;
  int s = v;
#pragma unroll
  for (int o = 1; o < 64; o <<= 1) {
    int u = __shfl_up(s, o);
    if (lane >= o) s += u;
  }
  __shared__ int wsum[2];
  if (lane == 63) wsum[wv] = s;
  __syncthreads();
  const int incl = ((wv == 1) ? wsum[0] : 0) + s;
  if (t < nb) bbase[t] = incl - v;
  if (t == 127) bbase[nb] = incl;
}

__global__ __launch_bounds__(256) void k_scan_c(
    const int* __restrict__ cnt, const int* __restrict__ bbase, int n, int nb,
    int* __restrict__ row, int* __restrict__ fill, float* __restrict__ inv) {
  int i = blockIdx.x * blockDim.x + threadIdx.x;
  if (i < n) {
    int v = row[i] + bbase[i >> 9];
    row[i] = v;
    fill[i] = v;
    int c = cnt[i];
    inv[i] = c > 0 ? 1.f / (float)c : 0.f;
  }
  if (i == 0) row[n] = bbase[nb];
}

// fill CSR incidence lists + direct neighbor lists (order arbitrary)
__global__ void k_fill(const int* __restrict__ nidx, const int* __restrict__ eidx,
                       int* __restrict__ fillN, int* __restrict__ fillE,
                       int* __restrict__ jlN, int* __restrict__ jlE,
                       int* __restrict__ elN, int* __restrict__ nlE) {
  int j = blockIdx.x * blockDim.x + threadIdx.x;
  if (j < NNZV) {
    int n = nidx[j], e = eidx[j];
    int p = atomicAdd(&fillN[n], 1);
    jlN[p] = j; elN[p] = e;
    int q = atomicAdd(&fillE[e], 1);
    jlE[q] = j; nlE[q] = n;
  }
}

// ---------------------------------------------------------------------------
// gather to edges (conv1): one wave per edge, x4-unrolled grouped loads.
__global__ __launch_bounds__(256) void k_gather_e(
    const int* __restrict__ rowE, const int* __restrict__ jlE,
    const int* __restrict__ nlE, const float* __restrict__ alpha,
    const float* __restrict__ xl, const float* __restrict__ Binv,
    float* __restrict__ msum) {
  int e = (blockIdx.x * blockDim.x + threadIdx.x) >> 6;
  int lane = threadIdx.x & 63;
  if (e >= N_EDGES) return;
  float acc[DSTALK];
#pragma unroll
  for (int r = 0; r < DSTALK; r++) acc[r] = 0.f;
  const int lo = rowE[e], hi = rowE[e + 1];
  int p = lo;
  for (; p + 3 < hi; p += 4) {
    int jj[4], nn[4];
#pragma unroll
    for (int u = 0; u < 4; u++) { jj[u] = jlE[p + u]; nn[u] = nlE[p + u]; }
    float v[4][DSTALK], a[4][DSTALK];
#pragma unroll
    for (int u = 0; u < 4; u++) {
      const float* __restrict__ xr = xl + (size_t)nn[u] * HD + lane;
      const float* __restrict__ ar = alpha + (size_t)jj[u] * DSTALK;
#pragma unroll
      for (int r = 0; r < DSTALK; r++) { v[u][r] = xr[r * HDIM]; a[u][r] = ar[r]; }
    }
#pragma unroll
    for (int r = 0; r < DSTALK; r++)
      acc[r] += a[0][r] * v[0][r] + a[1][r] * v[1][r] +
                a[2][r] * v[2][r] + a[3][r] * v[3][r];
  }
  for (; p < hi; p++) {
    const int j0 = jlE[p], n0 = nlE[p];
    const float* __restrict__ xr0 = xl + (size_t)n0 * HD + lane;
    const float* __restrict__ ar0 = alpha + (size_t)j0 * DSTALK;
#pragma unroll
    for (int r = 0; r < DSTALK; r++) acc[r] += ar0[r] * xr0[r * HDIM];
  }
  const float bv = Binv[e];
  float* __restrict__ mr = msum + (size_t)e * HD + lane;
#pragma unroll
  for (int r = 0; r < DSTALK; r++) mr[r * HDIM] = acc[r] * bv;
}

// gather back to nodes + bias + ELU epilogue: one wave per node, x4 unroll.
__global__ __launch_bounds__(256) void k_gather_n(
    const int* __restrict__ rowN, const int* __restrict__ jlN,
    const int* __restrict__ elN, const float* __restrict__ alpha,
    const float* __restrict__ msum, const float* __restrict__ Dinv,
    const float* __restrict__ xl, const float* __restrict__ bias,
    float* __restrict__ outp) {
  int n = (blockIdx.x * blockDim.x + threadIdx.x) >> 6;
  int lane = threadIdx.x & 63;
  if (n >= N_NODES) return;
  float acc[DSTALK];
#pragma unroll
  for (int r = 0; r < DSTALK; r++) acc[r] = 0.f;
  const int lo = rowN[n], hi = rowN[n + 1];
  int p = lo;
  for (; p + 3 < hi; p += 4) {
    int jj[4], ee[4];
#pragma unroll
    for (int u = 0; u < 4; u++) { jj[u] = jlN[p + u]; ee[u] = elN[p + u]; }
    float v[4][DSTALK], a[4][DSTALK];
#pragma unroll
    for (int u = 0; u < 4; u++) {
      const float* __restrict__ mr = msum + (size_t)ee[u] * HD + lane;
      const float* __restrict__ ar = alpha + (size_t)jj[u] * DSTALK;
#pragma unroll
      for (int r = 0; r < DSTALK; r++) { v[u][r] = mr[r * HDIM]; a[u][r] = ar[r]; }
    }
#pragma unroll
    for (int r = 0; r < DSTALK; r++)
      acc[r] += a[0][r] * v[0][r] + a[1][r] * v[1][r] +
                a[2][r] * v[2][r] + a[3][r] * v[3][r];
  }
  for (; p < hi; p++) {
    const int j0 = jlN[p], e0 = elN[p];
    const float* __restrict__ mr0 = msum + (size_t)e0 * HD + lane;
    const float* __restrict__ ar0 = alpha + (size_t)j0 * DSTALK;
#pragma unroll
    for (int r = 0; r < DSTALK; r++) acc[r] += ar0[r] * mr0[r * HDIM];
  }
  const float dv = Dinv[n];
  const float bb = bias[lane];
  const float* __restrict__ xr = xl + (size_t)n * HD + lane;
  float* __restrict__ orow = outp + (size_t)n * HD + lane;
#pragma unroll
  for (int r = 0; r < DSTALK; r++) {
    float v = xr[r * HDIM] + bb - dv * acc[r];
    orow[r * HDIM] = v > 0.f ? v : expm1f(v);
  }
}

// ---------------------------------------------------------------------------
extern "C" void kernel_launch(void* const* d_in, const int* in_sizes, int n_in,
                              void* d_out, int out_size, void* d_ws, size_t ws_size,
                              hipStream_t stream) {
  const float* x    = (const float*)d_in[0];
  const float* hea  = (const float*)d_in[1];
  const int*  nidx  = (const int*)d_in[2];
  const int*  eidx  = (const int*)d_in[3];
  // d_in[4], d_in[5] = node_types / hyperedge_types: unused by reference
  const float* W_lin = (const float*)d_in[6];
  const float* b_lin = (const float*)d_in[7];
  const float* ln_g  = (const float*)d_in[8];
  const float* ln_b  = (const float*)d_in[9];
  const float* W_sh  = (const float*)d_in[10];
  const float* b_sh  = (const float*)d_in[11];
  const float* W_c0  = (const float*)d_in[12];
  const float* b_c0  = (const float*)d_in[13];
  const float* W_c1  = (const float*)d_in[14];
  const float* b_c1  = (const float*)d_in[15];
  float* out = (float*)d_out;

  // workspace layout (f32), 256B aligned. Total ~105 MB.
  char* ws = (char*)d_ws;
  size_t off = 0;
  auto alloc = [&](size_t bytes) {
    size_t o = off;
    off = (off + bytes + 255) & ~(size_t)255;
    return o;
  };
  size_t o_xl0   = alloc((size_t)NROWS * HDIM * 4);               // 76.8 MB
  size_t o_msum  = alloc((size_t)EROWS * HDIM * 4);               // 15.36 MB
  size_t o_alpha = alloc((size_t)NNZV * DSTALK * 4);              // 6 MB
  size_t o_stats = alloc((size_t)(N_NODES + N_EDGES) * 8 * 4);    // 1.92 MB
  size_t o_jlN   = alloc((size_t)NNZV * 4);                       // 1 MB
  size_t o_jlE   = alloc((size_t)NNZV * 4);                       // 1 MB
  size_t o_elN   = alloc((size_t)NNZV * 4);                       // 1 MB
  size_t o_nlE   = alloc((size_t)NNZV * 4);                       // 1 MB
  size_t o_cntN  = alloc((size_t)N_NODES * 4);
  size_t o_cntE  = alloc((size_t)N_EDGES * 4);
  size_t o_rowN  = alloc((size_t)(N_NODES + 1) * 4);
  size_t o_rowE  = alloc((size_t)(N_EDGES + 1) * 4);
  size_t o_filN  = alloc((size_t)N_NODES * 4);
  size_t o_filE  = alloc((size_t)N_EDGES * 4);
  size_t o_Dinv  = alloc((size_t)N_NODES * 4);
  size_t o_Binv  = alloc((size_t)N_EDGES * 4);
  size_t o_bsN   = alloc((size_t)256 * 4);
  size_t o_bbN   = alloc((size_t)256 * 4);
  size_t o_bsE   = alloc((size_t)256 * 4);
  size_t o_bbE   = alloc((size_t)256 * 4);
  size_t o_WeffT = alloc((size_t)IN_CH * HD * 4);                 // 196 KB
  size_t o_Wm    = alloc((size_t)IN_CH * HDIM * 4);               // 32 KB
  size_t o_cm    = alloc((size_t)HDIM * 4);
  size_t o_c0    = alloc((size_t)HD * 4);
  size_t o_gwN   = alloc((size_t)64 * DSTALK * 4);
  size_t o_gwE   = alloc((size_t)64 * DSTALK * 4);
  size_t o_G     = alloc((size_t)DSTALK * 4);
  size_t o_K     = alloc((size_t)DSTALK * 4);
  size_t o_W1T   = alloc((size_t)HDIM * HDIM * 4);                // 16 KB

  float* xl0    = (float*)(ws + o_xl0);
  float* msum   = (float*)(ws + o_msum);
  float* alpha  = (float*)(ws + o_alpha);
  float* stats  = (float*)(ws + o_stats);
  int*   jlN    = (int*)(ws + o_jlN);
  int*   jlE    = (int*)(ws + o_jlE);
  int*   elN    = (int*)(ws + o_elN);
  int*   nlE    = (int*)(ws + o_nlE);
  int*   cntN   = (int*)(ws + o_cntN);
  int*   cntE   = (int*)(ws + o_cntE);
  int*   rowN   = (int*)(ws + o_rowN);
  int*   rowE   = (int*)(ws + o_rowE);
  int*   filN   = (int*)(ws + o_filN);
  int*   filE   = (int*)(ws + o_filE);
  float* Dinv   = (float*)(ws + o_Dinv);
  float* Binv   = (float*)(ws + o_Binv);
  int*   bsN    = (int*)(ws + o_bsN);
  int*   bbN    = (int*)(ws + o_bbN);
  int*   bsE    = (int*)(ws + o_bsE);
  int*   bbE    = (int*)(ws + o_bbE);
  float* W0effT = (float*)(ws + o_WeffT);
  float* Wm     = (float*)(ws + o_Wm);
  float* cm     = (float*)(ws + o_cm);
  float* c0     = (float*)(ws + o_c0);
  float* gwN    = (float*)(ws + o_gwN);
  float* gwE    = (float*)(ws + o_gwE);
  float* G      = (float*)(ws + o_G);
  float* K      = (float*)(ws + o_K);
  float* W1T    = (float*)(ws + o_W1T);

  // d_out (76.8MB) doubles as scratch, all consumed before the final write:
  // ax [0, 30.72MB); xh @32MiB (12.8MB); xl @48MiB (12.8MB); wh @64MiB; wl @66MiB.
  float* ax = (float*)d_out;
  unsigned short* xh  = (unsigned short*)((char*)d_out + ((size_t)32 << 20));
  unsigned short* xlo = (unsigned short*)((char*)d_out + ((size_t)48 << 20));
  unsigned short* wh  = (unsigned short*)((char*)d_out + ((size_t)64 << 20));
  unsigned short* wl  = (unsigned short*)((char*)d_out + ((size_t)66 << 20));

  const int NB_N = (N_NODES + 511) / 512;  // 98
  const int NB_E = (N_EDGES + 511) / 512;  // 20

  // 0. weight prep + bf16 splits
  k_wefft<<<(IN_CH * HD + 255) / 256, 256, 0, stream>>>(W_lin, W_c0, W0effT);
  k_wsmall<<<(WS_END + 255) / 256, 256, 0, stream>>>(
      W_lin, b_lin, W_c0, W_c1, ln_g, ln_b, W_sh, b_sh,
      Wm, cm, c0, gwN, gwE, G, K, W1T);
  k_split<<<((N_NODES * IN_CH / 4) + 255) / 256, 256, 0, stream>>>(
      x, N_NODES * IN_CH / 4, xh, xlo);
  k_split<<<((HD * IN_CH / 4) + 255) / 256, 256, 0, stream>>>(
      W0effT, HD * IN_CH / 4, wh, wl);

  // 1. CSR build: counts -> parallel scans (+Dinv/Binv) -> fill
  hipMemsetAsync(ws + o_cntN, 0, (size_t)N_NODES * 4, stream);
  hipMemsetAsync(ws + o_cntE, 0, (size_t)N_EDGES * 4, stream);
  k_count<<<(NNZV + 255) / 256, 256, 0, stream>>>(nidx, eidx, cntN, cntE);
  k_scan_a<<<NB_N, 256, 0, stream>>>(cntN, N_NODES, rowN, bsN);
  k_scan_a<<<NB_E, 256, 0, stream>>>(cntE, N_EDGES, rowE, bsE);
  k_scan_b<<<1, 128, 0, stream>>>(bsN, NB_N, bbN);
  k_scan_b<<<1, 128, 0, stream>>>(bsE, NB_E, bbE);
  k_scan_c<<<(N_NODES + 255) / 256, 256, 0, stream>>>(cntN, bbN, N_NODES, NB_N,
                                                      rowN, filN, Dinv);
  k_scan_c<<<(N_EDGES + 255) / 256, 256, 0, stream>>>(cntE, bbE, N_EDGES, NB_E,
                                                      rowE, filE, Binv);
  k_fill<<<(NNZV + 255) / 256, 256, 0, stream>>>(nidx, eidx, filN, filE,
                                                 jlN, jlE, elN, nlE);

  // 2. fused stalk-mean + LN sufficient stats
  k_xa_stats<<<(N_NODES + N_EDGES + 63) / 64, 256, 0, stream>>>(
      x, hea, Wm, cm, gwN, gwE, stats);

  // 3. closed-form sheaf coefficients alpha [NNZ x 6]
  k_sheaf2<<<(NNZV + 255) / 256, 256, 0, stream>>>(nidx, eidx, stats, G, K, alpha);

  // 4. conv0 (factorized): gather x-space edge aggregates -> edge GEMM -> msum;
  //    node GEMM xl0 (split-bf16 MFMA); node gather + bias + ELU.
  k_gather_ex<<<(N_EDGES + 3) / 4, 256, 0, stream>>>(rowE, jlE, nlE, alpha, x,
                                                     Binv, ax);
  {
    dim3 ge((N_EDGES + 127) / 128, DSTALK);  // (79, 6)
    k_edge_gemm<<<ge, 256, 0, stream>>>(ax, W0effT, msum);
  }
  {
    dim3 g((N_NODES + 127) / 128, HD / 128);   // (391, 3)
    k_xl0<<<g, 256, 0, stream>>>(xh, xlo, wh, wl, c0, xl0);
  }
  k_gather_n<<<(N_NODES + 3) / 4, 256, 0, stream>>>(rowN, jlN, elN, alpha, msum, Dinv,
                                                    xl0, b_c0, xl0);  // xl0 now holds h1

  // 5. conv1: xl1 = h1@W1 (in place); gather-diffusion; bias+ELU into d_out
  k_xw<<<(NROWS + 127) / 128, 256, 0, stream>>>(xl0, W1T, xl0);
  k_gather_e<<<(N_EDGES + 3) / 4, 256, 0, stream>>>(rowE, jlE, nlE, alpha, xl0, Binv, msum);
  k_gather_n<<<(N_NODES + 3) / 4, 256, 0, stream>>>(rowN, jlN, elN, alpha, msum, Dinv,
                                                    xl0, b_c1, out);

  (void)in_sizes; (void)n_in; (void)out_size; (void)ws_size;
}